// Round 4
// baseline (8153.078 us; speedup 1.0000x reference)
//
#include <hip/hip_runtime.h>
#include <cstdint>
#include <cstddef>

typedef unsigned short u16;
typedef __attribute__((ext_vector_type(8))) short bf16x8;  // 8 x bf16 (4 VGPRs)
typedef __attribute__((ext_vector_type(4))) float f32x4;

#define DEV __device__ __forceinline__

DEV float bf2f(u16 h) { union { unsigned int u; float f; } x; x.u = ((unsigned int)h) << 16; return x.f; }
DEV u16 f2bf(float f) {
    union { float f; unsigned int u; } x; x.f = f;
    unsigned int u = x.u;
    return (u16)((u + 0x7fffu + ((u >> 16) & 1u)) >> 16);   // RNE
}
DEV float sigf(float x) { return 1.0f / (1.0f + expf(-x)); }
DEV f32x4 mfma16(bf16x8 a, bf16x8 b, f32x4 c) {
    return __builtin_amdgcn_mfma_f32_16x16x32_bf16(a, b, c, 0, 0, 0);
}

// B=256, T=256, E=128, H=128 (per direction), H2=256. ALL tensors fp32.
// Time chunked (CHv = 64 or 32 chosen from ws_size) for the xg buffers.

// ---------------------------------------------------------------------------
// xg GEMM, first (bi) layer, fp32 in/out.
// out[tl*256+b, n] = bias[n] + sum_e embed[b,t0+tl,e]*Wih[n,e]
// A (embed) split hi/lo bf16 -> logical K = 256; W single bf16.
// grid = (8, 2*CHv*4): lower half fwd, upper half rev.
// ---------------------------------------------------------------------------
__global__ __launch_bounds__(256) void xg_fr_kernel(
    const float* __restrict__ embed,
    const float* __restrict__ Wf, const float* __restrict__ bf_,
    const float* __restrict__ Wr, const float* __restrict__ br_,
    float* __restrict__ xgf, float* __restrict__ xgr, int t0f, int t0r)
{
    __shared__ __align__(16) u16 As[64][40];
    __shared__ __align__(16) u16 Bs[64][40];
    int tid = threadIdx.x;
    int bx = blockIdx.x;
    int by = blockIdx.y;
    int half = gridDim.y >> 1;
    bool isR = by >= half;
    int m0 = (by - (isR ? half : 0)) * 64;
    const float* W    = isR ? Wr  : Wf;
    const float* bias = isR ? br_ : bf_;
    float* out        = isR ? xgr : xgf;
    int tbase         = isR ? t0r : t0f;
    int n0 = bx * 64;

    int r  = tid >> 2;            // 0..63 staging row
    int kc = (tid & 3) * 8;       // 0,8,16,24
    int m  = m0 + r;
    int tl = m >> 8, bb = m & 255;
    const float* arow = embed + ((size_t)(bb * 256 + (tbase + tl)) * 128);
    const float* brow = W + ((size_t)(n0 + r) * 128);

    f32x4 acc[4];
    #pragma unroll
    for (int i = 0; i < 4; ++i) acc[i] = (f32x4){0.f, 0.f, 0.f, 0.f};
    int lane = tid & 63, w = tid >> 6;
    int fr_ = lane & 15, kb0 = (lane >> 4) * 8;

    for (int kt = 0; kt < 8; ++kt) {
        int sc = (kt & 3) * 32 + kc;       // source col 0..127
        bool lo = kt >= 4;
        f32x4 va = *(const f32x4*)(arow + sc);
        f32x4 vb = *(const f32x4*)(arow + sc + 4);
        f32x4 wa = *(const f32x4*)(brow + sc);
        f32x4 wb = *(const f32x4*)(brow + sc + 4);
        bf16x8 hv, wv;
        #pragma unroll
        for (int i = 0; i < 8; ++i) {
            float v = (i < 4) ? va[i] : vb[i - 4];
            u16 hi = f2bf(v);
            hv[i] = (short)(lo ? f2bf(v - bf2f(hi)) : hi);
            float wf = (i < 4) ? wa[i] : wb[i - 4];
            wv[i] = (short)f2bf(wf);
        }
        *(bf16x8*)&As[r][kc] = hv;
        *(bf16x8*)&Bs[r][kc] = wv;
        __syncthreads();
        bf16x8 bfrg = *(const bf16x8*)&Bs[w * 16 + fr_][kb0];
        #pragma unroll
        for (int mt = 0; mt < 4; ++mt) {
            bf16x8 afrg = *(const bf16x8*)&As[mt * 16 + fr_][kb0];
            acc[mt] = mfma16(afrg, bfrg, acc[mt]);
        }
        __syncthreads();
    }
    int col = n0 + w * 16 + fr_;
    float bvv = bias[col];
    int rq = (lane >> 4) * 4;
    #pragma unroll
    for (int mt = 0; mt < 4; ++mt)
        #pragma unroll
        for (int rr = 0; rr < 4; ++rr) {
            int mrow = m0 + mt * 16 + rq + rr;
            out[(size_t)mrow * 512 + col] = acc[mt][rr] + bvv;
        }
}

// ---------------------------------------------------------------------------
// xg GEMM, H2 layers, fp32 in/out. X split hi/lo (logical K=512 over 256).
// grid = (16, CHv*4)
// ---------------------------------------------------------------------------
__global__ __launch_bounds__(256) void xg_l_kernel(
    const float* __restrict__ X, const float* __restrict__ W,
    const float* __restrict__ bias, float* __restrict__ out, int t0)
{
    __shared__ __align__(16) u16 As[64][40];
    __shared__ __align__(16) u16 Bs[64][40];
    int tid = threadIdx.x;
    int bx = blockIdx.x;          // 0..15
    int by = blockIdx.y;
    int m0 = by * 64, n0 = bx * 64;
    int r  = tid >> 2;
    int kc = (tid & 3) * 8;
    int m  = m0 + r;
    int tl = m >> 8, bb = m & 255;
    const float* arow = X + ((size_t)((t0 + tl) * 256 + bb) * 256);
    const float* brow = W + ((size_t)(n0 + r) * 256);

    f32x4 acc[4];
    #pragma unroll
    for (int i = 0; i < 4; ++i) acc[i] = (f32x4){0.f, 0.f, 0.f, 0.f};
    int lane = tid & 63, w = tid >> 6;
    int fr_ = lane & 15, kb0 = (lane >> 4) * 8;

    for (int kt = 0; kt < 16; ++kt) {
        int sc = (kt & 7) * 32 + kc;       // source col 0..255
        bool lo = kt >= 8;
        f32x4 va = *(const f32x4*)(arow + sc);
        f32x4 vb = *(const f32x4*)(arow + sc + 4);
        f32x4 wa = *(const f32x4*)(brow + sc);
        f32x4 wb = *(const f32x4*)(brow + sc + 4);
        bf16x8 hv, wv;
        #pragma unroll
        for (int i = 0; i < 8; ++i) {
            float v = (i < 4) ? va[i] : vb[i - 4];
            u16 hi = f2bf(v);
            hv[i] = (short)(lo ? f2bf(v - bf2f(hi)) : hi);
            float wf = (i < 4) ? wa[i] : wb[i - 4];
            wv[i] = (short)f2bf(wf);
        }
        *(bf16x8*)&As[r][kc] = hv;
        *(bf16x8*)&Bs[r][kc] = wv;
        __syncthreads();
        bf16x8 bfrg = *(const bf16x8*)&Bs[w * 16 + fr_][kb0];
        #pragma unroll
        for (int mt = 0; mt < 4; ++mt) {
            bf16x8 afrg = *(const bf16x8*)&As[mt * 16 + fr_][kb0];
            acc[mt] = mfma16(afrg, bfrg, acc[mt]);
        }
        __syncthreads();
    }
    int col = n0 + w * 16 + fr_;
    float bvv = bias[col];
    int rq = (lane >> 4) * 4;
    #pragma unroll
    for (int mt = 0; mt < 4; ++mt)
        #pragma unroll
        for (int rr = 0; rr < 4; ++rr) {
            int mrow = m0 + mt * 16 + rq + rr;
            out[(size_t)mrow * 1024 + col] = acc[mt][rr] + bvv;
        }
}

// ---------------------------------------------------------------------------
// layernorm over 256 channels, one wave per row. RESID adds R first. In-place.
// ---------------------------------------------------------------------------
template<int RESID>
__global__ __launch_bounds__(256) void ln_kernel(
    float* __restrict__ X, const float* __restrict__ R,
    const float* __restrict__ gw, const float* __restrict__ bw)
{
    int row  = blockIdx.x * 4 + (threadIdx.x >> 6);
    int lane = threadIdx.x & 63;
    float* xr = X + (size_t)row * 256;
    f32x4 v = *(const f32x4*)(xr + lane * 4);
    if (RESID) {
        f32x4 u = *(const f32x4*)(R + (size_t)row * 256 + lane * 4);
        v += u;
    }
    float s = v[0] + v[1] + v[2] + v[3];
    #pragma unroll
    for (int mm = 1; mm < 64; mm <<= 1) s += __shfl_xor(s, mm, 64);
    float mu = s * (1.0f / 256.0f);
    f32x4 e = v - mu;
    float q = e[0]*e[0] + e[1]*e[1] + e[2]*e[2] + e[3]*e[3];
    #pragma unroll
    for (int mm = 1; mm < 64; mm <<= 1) q += __shfl_xor(q, mm, 64);
    float rs = rsqrtf(q * (1.0f / 256.0f) + 1e-5f);
    int c0 = lane * 4;
    f32x4 o;
    #pragma unroll
    for (int i = 0; i < 4; ++i) o[i] = e[i] * rs * gw[c0 + i] + bw[c0 + i];
    *(f32x4*)(xr + lane * 4) = o;
}

// ---------------------------------------------------------------------------
// Persistent LSTM recurrence over one time chunk [s0,s1).
// MODE 0: bi H=128 layer, 256 wgs: bid<128 fwd, else rev.
//         Per dir: 32 groups x GROUP=4 wgs; MB=8 samples, JC=32 h-cols/wg.
// MODE 1: H2 layer -> xout. 16 groups x GROUP=16; MB=16, JC=16.
// MODE 2: H2 layer -> y at t==lastidx[b] (bn+relu, fp32 out).
// Whh LDS-resident (fp32->bf16 once per launch). h exchanged as packed
// bf16 hi/lo u32 via agent-scope atomics; per-wg flag counters (release
// after barrier-drained stores). c in registers, persisted in cbuf across
// chunk launches. Grid = 256 wgs <= 256 CUs -> co-resident, no deadlock.
// ---------------------------------------------------------------------------
template<int MODE>
__global__ __launch_bounds__(256) void recur_kernel(
    const float* __restrict__ xg0, const float* __restrict__ xg1,
    const float* __restrict__ whh0, const float* __restrict__ whh1,
    float* __restrict__ cb0, float* __restrict__ cb1,
    unsigned int* hb0, unsigned int* hb1,
    unsigned int* fl0, unsigned int* fl1,
    float* __restrict__ xout, float* __restrict__ yout,
    const int* __restrict__ lastidx,
    const float* __restrict__ bng, const float* __restrict__ bnb,
    int s0, int s1)
{
    constexpr int MB    = (MODE == 0) ? 8 : 16;    // samples per group
    constexpr int JC    = (MODE == 0) ? 32 : 16;   // h-cols per wg
    constexpr int GROUP = (MODE == 0) ? 4 : 16;    // wgs per group
    constexpr int K     = (MODE == 0) ? 128 : 256; // hidden size
    constexpr int NW    = 4 * JC;                  // gate rows per wg
    constexpr int M     = 2 * MB;                  // hi+lo stacked rows
    constexpr int N4    = 4 * K;                   // xg row width

    __shared__ __align__(16) u16  Wl[NW][K + 8];
    __shared__ __align__(16) u16  Al[M][K + 8];
    __shared__ __align__(16) float Gl[M][NW + 4];

    int tid = threadIdx.x, lane = tid & 63, w = tid >> 6;
    int bid = blockIdx.x;

    const float* xg; const float* whh; float* cb; unsigned int* hb; unsigned int* fl;
    int coloff = 0, rev = 0, lb;
    if (MODE == 0) {
        if (bid < 128) { lb = bid;       xg = xg0; whh = whh0; cb = cb0; hb = hb0; fl = fl0; coloff = 0;   rev = 0; }
        else           { lb = bid - 128; xg = xg1; whh = whh1; cb = cb1; hb = hb1; fl = fl1; coloff = 128; rev = 1; }
    } else { lb = bid; xg = xg0; whh = whh0; cb = cb0; hb = hb0; fl = fl0; }
    int group = lb / GROUP;
    int cw    = lb % GROUP;
    unsigned int* hbg = hb + (size_t)group * (2 * MB * K);
    unsigned int* flg = fl + (size_t)group * (GROUP * 16);

    // stage Whh slice (fp32 -> bf16): LDS row n=g*JC+jj <- Whh[g*K + cw*JC+jj, :]
    for (int idx = tid; idx < NW * (K / 8); idx += 256) {
        int n = idx / (K / 8), kv = (idx % (K / 8)) * 8;
        int g = n / JC, jj = n % JC;
        const float* src = whh + (size_t)(g * K + cw * JC + jj) * K + kv;
        f32x4 a = *(const f32x4*)src;
        f32x4 b = *(const f32x4*)(src + 4);
        bf16x8 wv;
        #pragma unroll
        for (int i = 0; i < 8; ++i) wv[i] = (short)f2bf((i < 4) ? a[i] : b[i - 4]);
        *(bf16x8*)&Wl[n][kv] = wv;
    }

    int s   = tid / JC;            // sample-local 0..MB-1
    int jc  = tid % JC;
    int bsamp = group * MB + s;
    int col   = cw * JC + jc;
    float c = (s0 > 0) ? cb[(size_t)bsamp * K + col] : 0.f;
    int lastb = -1; float bngv = 0.f, bnbv = 0.f;
    if (MODE == 2) {
        bool is64 = (lastidx[1] | lastidx[3] | lastidx[5] | lastidx[7] |
                     lastidx[9] | lastidx[11] | lastidx[13] | lastidx[15]) == 0;
        lastb = is64 ? lastidx[2 * bsamp] : lastidx[bsamp];
        bngv = bng[col] * rsqrtf(1.0f + 1e-5f);
        bnbv = bnb[col];
    }
    int fr_ = lane & 15, kb0 = (lane >> 4) * 8, rq = (lane >> 4) * 4;
    __syncthreads();

    for (int t = s0; t < s1; ++t) {
        int xrow = rev ? (s1 - 1 - t) : (t - s0);
        const float* xp = xg + ((size_t)(xrow * 256 + bsamp)) * N4 + col;
        float xv0 = xp[0], xv1 = xp[K], xv2 = xp[2 * K], xv3 = xp[3 * K];
        float g0, g1, g2, g3;

        if (t > 0) {
            if (tid < GROUP) {
                unsigned int* fp = flg + tid * 16;
                while (__hip_atomic_load(fp, __ATOMIC_RELAXED, __HIP_MEMORY_SCOPE_AGENT) < (unsigned int)t)
                    __builtin_amdgcn_s_sleep(1);
            }
            __syncthreads();
            const unsigned int* hsrc = hbg + (size_t)(t & 1) * (MB * K);
            constexpr int CNT = MB * K / 256;
            #pragma unroll
            for (int i = 0; i < CNT; ++i) {
                int idx = tid + i * 256;
                int sa = idx / K, k = idx % K;
                unsigned int v = __hip_atomic_load(hsrc + idx, __ATOMIC_RELAXED, __HIP_MEMORY_SCOPE_AGENT);
                Al[sa][k]      = (u16)(v & 0xffffu);
                Al[MB + sa][k] = (u16)(v >> 16);
            }
            __syncthreads();
            f32x4 acc0 = (f32x4){0.f, 0.f, 0.f, 0.f};
            f32x4 acc1 = (f32x4){0.f, 0.f, 0.f, 0.f};
            #pragma unroll
            for (int kt = 0; kt < K / 32; ++kt) {
                int kb = kt * 32 + kb0;
                if (MODE == 0) {
                    bf16x8 a  = *(const bf16x8*)&Al[fr_][kb];
                    bf16x8 b0 = *(const bf16x8*)&Wl[(2 * w) * 16 + fr_][kb];
                    bf16x8 b1 = *(const bf16x8*)&Wl[(2 * w + 1) * 16 + fr_][kb];
                    acc0 = mfma16(a, b0, acc0);
                    acc1 = mfma16(a, b1, acc1);
                } else {
                    bf16x8 b  = *(const bf16x8*)&Wl[w * 16 + fr_][kb];
                    bf16x8 a0 = *(const bf16x8*)&Al[fr_][kb];
                    bf16x8 a1 = *(const bf16x8*)&Al[16 + fr_][kb];
                    acc0 = mfma16(a0, b, acc0);
                    acc1 = mfma16(a1, b, acc1);
                }
            }
            #pragma unroll
            for (int rr = 0; rr < 4; ++rr) {
                if (MODE == 0) {
                    Gl[rq + rr][(2 * w) * 16 + fr_]     = acc0[rr];
                    Gl[rq + rr][(2 * w + 1) * 16 + fr_] = acc1[rr];
                } else {
                    Gl[rq + rr][w * 16 + fr_]      = acc0[rr];
                    Gl[16 + rq + rr][w * 16 + fr_] = acc1[rr];
                }
            }
            __syncthreads();
            g0 = xv0 + Gl[s][0 * JC + jc] + Gl[MB + s][0 * JC + jc];
            g1 = xv1 + Gl[s][1 * JC + jc] + Gl[MB + s][1 * JC + jc];
            g2 = xv2 + Gl[s][2 * JC + jc] + Gl[MB + s][2 * JC + jc];
            g3 = xv3 + Gl[s][3 * JC + jc] + Gl[MB + s][3 * JC + jc];
        } else {
            g0 = xv0; g1 = xv1; g2 = xv2; g3 = xv3;
        }

        c = sigf(g1) * c + sigf(g0) * tanhf(g2);
        float h = sigf(g3) * tanhf(c);

        if (MODE == 0) {
            int tt = rev ? (255 - t) : t;
            xout[((size_t)tt * 256 + bsamp) * 256 + coloff + col] = h;
        } else if (MODE == 1) {
            xout[((size_t)t * 256 + bsamp) * 256 + col] = h;
        } else {
            if (t == lastb) {
                float y = h * bngv + bnbv;
                y = y > 0.f ? y : 0.f;
                yout[(size_t)bsamp * 256 + col] = y;
            }
        }

        u16 hh = f2bf(h);
        u16 hl = f2bf(h - bf2f(hh));
        unsigned int word = (unsigned int)hh | ((unsigned int)hl << 16);
        __hip_atomic_store(hbg + (size_t)((t + 1) & 1) * (MB * K) + (size_t)s * K + col,
                           word, __ATOMIC_RELAXED, __HIP_MEMORY_SCOPE_AGENT);
        __syncthreads();   // drains vmcnt before flag release
        if (tid == 0)
            __hip_atomic_store(flg + cw * 16, (unsigned int)(t + 1),
                               __ATOMIC_RELEASE, __HIP_MEMORY_SCOPE_AGENT);
    }
    cb[(size_t)bsamp * K + col] = c;
}

// ---------------------------------------------------------------------------
// Launch
// ---------------------------------------------------------------------------
extern "C" void kernel_launch(void* const* d_in, const int* in_sizes, int n_in,
                              void* d_out, int out_size, void* d_ws, size_t ws_size,
                              hipStream_t stream)
{
    (void)in_sizes; (void)n_in; (void)out_size;
    const float* embed = (const float*)d_in[0];
    const int* lastidx = (const int*)d_in[1];
    const float* Wih_f = (const float*)d_in[2];
    const float* Whh_f = (const float*)d_in[3];
    const float* b_f   = (const float*)d_in[4];
    const float* Wih_r = (const float*)d_in[5];
    const float* Whh_r = (const float*)d_in[6];
    const float* b_r   = (const float*)d_in[7];
    const float* ln1g  = (const float*)d_in[8];
    const float* ln1b  = (const float*)d_in[9];
    const float* W1ih  = (const float*)d_in[10];
    const float* W1hh  = (const float*)d_in[11];
    const float* b1    = (const float*)d_in[12];
    const float* ln2g  = (const float*)d_in[13];
    const float* ln2b  = (const float*)d_in[14];
    const float* W2ih  = (const float*)d_in[15];
    const float* W2hh  = (const float*)d_in[16];
    const float* b2    = (const float*)d_in[17];
    const float* bng   = (const float*)d_in[18];
    const float* bnb   = (const float*)d_in[19];

    const size_t MiB = 1024 * 1024;
    // CH=64 layout needs ~194.4 MiB; round-3 only proved ws >= ~193 MiB, so
    // fall back to CH=32 (162.4 MiB) when ws is tight. ws_size is constant
    // across calls -> capture-safe branch.
    const int  CHv = (ws_size >= 196 * MiB) ? 64 : 32;
    const int  nch = 256 / CHv;
    char* ws = (char*)d_ws;
    const size_t xgBytes = (size_t)CHv * 256 * 1024 * 4;   // 64 or 32 MiB

    float* XG  = (float*)ws;
    float* XGr = XG + (size_t)CHv * 256 * 512;             // stage-1 rev half
    float* X1  = (float*)(ws + xgBytes);                   // 64 MiB
    float* X2  = (float*)(ws + xgBytes + 64 * MiB);        // 64 MiB
    char*  p   = ws + xgBytes + 128 * MiB;
    unsigned int* hbf = (unsigned int*)p;       p += 256 * 1024;
    unsigned int* hbr = (unsigned int*)p;       p += 256 * 1024;
    unsigned int* hb1 = (unsigned int*)p;       p += 512 * 1024;
    unsigned int* hb2 = (unsigned int*)p;       p += 512 * 1024;
    float* cbf = (float*)p;                     p += 128 * 1024;
    float* cbr = (float*)p;                     p += 128 * 1024;
    float* cb1 = (float*)p;                     p += 256 * 1024;
    float* cb2 = (float*)p;                     p += 256 * 1024;
    unsigned int* flf = (unsigned int*)p;       // 8 KiB
    unsigned int* flr = flf + 2048;             // 8 KiB
    unsigned int* fl1 = flr + 2048;             // 16 KiB
    unsigned int* fl2 = fl1 + 4096;             // 16 KiB

    hipMemsetAsync((void*)flf, 0, 48 * 1024, stream);

    // stage 1: bidirectional H=128 LSTM -> X1 (raw concat)
    for (int i = 0; i < nch; ++i) {
        xg_fr_kernel<<<dim3(8, 2 * CHv * 4), 256, 0, stream>>>(
            embed, Wih_f, b_f, Wih_r, b_r, XG, XGr, CHv * i, 256 - CHv * (i + 1));
        recur_kernel<0><<<256, 256, 0, stream>>>(
            XG, XGr, Whh_f, Whh_r, cbf, cbr, hbf, hbr, flf, flr,
            X1, nullptr, nullptr, nullptr, nullptr, CHv * i, CHv * (i + 1));
    }
    ln_kernel<0><<<16384, 256, 0, stream>>>(X1, nullptr, ln1g, ln1b);

    // stage 2: H2 LSTM layer 1 -> X2 (raw)
    for (int i = 0; i < nch; ++i) {
        xg_l_kernel<<<dim3(16, CHv * 4), 256, 0, stream>>>(X1, W1ih, b1, XG, CHv * i);
        recur_kernel<1><<<256, 256, 0, stream>>>(
            XG, nullptr, W1hh, nullptr, cb1, nullptr, hb1, nullptr, fl1, nullptr,
            X2, nullptr, nullptr, nullptr, nullptr, CHv * i, CHv * (i + 1));
    }
    ln_kernel<1><<<16384, 256, 0, stream>>>(X2, X1, ln2g, ln2b);

    // stage 3: H2 LSTM layer 2 -> gathered y (fp32 out)
    for (int i = 0; i < nch; ++i) {
        xg_l_kernel<<<dim3(16, CHv * 4), 256, 0, stream>>>(X2, W2ih, b2, XG, CHv * i);
        recur_kernel<2><<<256, 256, 0, stream>>>(
            XG, nullptr, W2hh, nullptr, cb2, nullptr, hb2, nullptr, fl2, nullptr,
            nullptr, (float*)d_out, lastidx, bng, bnb, CHv * i, CHv * (i + 1));
    }
}

// Round 6
// 3068.352 us; speedup vs baseline: 2.6572x; 2.6572x over previous
//
#include <hip/hip_runtime.h>
#include <cstdint>
#include <cstddef>

typedef unsigned short u16;
typedef unsigned long long u64;
typedef __attribute__((ext_vector_type(8))) short bf16x8;  // 8 x bf16 (4 VGPRs)
typedef __attribute__((ext_vector_type(4))) float f32x4;

#define DEV __device__ __forceinline__

DEV float bf2f(u16 h) { union { unsigned int u; float f; } x; x.u = ((unsigned int)h) << 16; return x.f; }
DEV u16 f2bf(float f) {
    union { float f; unsigned int u; } x; x.f = f;
    unsigned int u = x.u;
    return (u16)((u + 0x7fffu + ((u >> 16) & 1u)) >> 16);   // RNE
}
DEV float sigf(float x) { return 1.0f / (1.0f + expf(-x)); }
DEV f32x4 mfma16(bf16x8 a, bf16x8 b, f32x4 c) {
    return __builtin_amdgcn_mfma_f32_16x16x32_bf16(a, b, c, 0, 0, 0);
}

// B=256, T=256, E=128, H=128 (per direction), H2=256. ALL tensors fp32.
// Time chunked (CHv = 64 or 32 chosen from ws_size) for the xg buffers.

// ---------------------------------------------------------------------------
// xg GEMM, first (bi) layer, fp32 in/out.
// out[tl*256+b, n] = bias[n] + sum_e embed[b,t0+tl,e]*Wih[n,e]
// A (embed) split hi/lo bf16 -> logical K = 256; W single bf16.
// grid = (8, 2*CHv*4): lower half fwd, upper half rev.
// ---------------------------------------------------------------------------
__global__ __launch_bounds__(256) void xg_fr_kernel(
    const float* __restrict__ embed,
    const float* __restrict__ Wf, const float* __restrict__ bf_,
    const float* __restrict__ Wr, const float* __restrict__ br_,
    float* __restrict__ xgf, float* __restrict__ xgr, int t0f, int t0r)
{
    __shared__ __align__(16) u16 As[64][40];
    __shared__ __align__(16) u16 Bs[64][40];
    int tid = threadIdx.x;
    int bx = blockIdx.x;
    int by = blockIdx.y;
    int half = gridDim.y >> 1;
    bool isR = by >= half;
    int m0 = (by - (isR ? half : 0)) * 64;
    const float* W    = isR ? Wr  : Wf;
    const float* bias = isR ? br_ : bf_;
    float* out        = isR ? xgr : xgf;
    int tbase         = isR ? t0r : t0f;
    int n0 = bx * 64;

    int r  = tid >> 2;            // 0..63 staging row
    int kc = (tid & 3) * 8;       // 0,8,16,24
    int m  = m0 + r;
    int tl = m >> 8, bb = m & 255;
    const float* arow = embed + ((size_t)(bb * 256 + (tbase + tl)) * 128);
    const float* brow = W + ((size_t)(n0 + r) * 128);

    f32x4 acc[4];
    #pragma unroll
    for (int i = 0; i < 4; ++i) acc[i] = (f32x4){0.f, 0.f, 0.f, 0.f};
    int lane = tid & 63, w = tid >> 6;
    int fr_ = lane & 15, kb0 = (lane >> 4) * 8;

    for (int kt = 0; kt < 8; ++kt) {
        int sc = (kt & 3) * 32 + kc;       // source col 0..127
        bool lo = kt >= 4;
        f32x4 va = *(const f32x4*)(arow + sc);
        f32x4 vb = *(const f32x4*)(arow + sc + 4);
        f32x4 wa = *(const f32x4*)(brow + sc);
        f32x4 wb = *(const f32x4*)(brow + sc + 4);
        bf16x8 hv, wv;
        #pragma unroll
        for (int i = 0; i < 8; ++i) {
            float v = (i < 4) ? va[i] : vb[i - 4];
            u16 hi = f2bf(v);
            hv[i] = (short)(lo ? f2bf(v - bf2f(hi)) : hi);
            float wf = (i < 4) ? wa[i] : wb[i - 4];
            wv[i] = (short)f2bf(wf);
        }
        *(bf16x8*)&As[r][kc] = hv;
        *(bf16x8*)&Bs[r][kc] = wv;
        __syncthreads();
        bf16x8 bfrg = *(const bf16x8*)&Bs[w * 16 + fr_][kb0];
        #pragma unroll
        for (int mt = 0; mt < 4; ++mt) {
            bf16x8 afrg = *(const bf16x8*)&As[mt * 16 + fr_][kb0];
            acc[mt] = mfma16(afrg, bfrg, acc[mt]);
        }
        __syncthreads();
    }
    int col = n0 + w * 16 + fr_;
    float bvv = bias[col];
    int rq = (lane >> 4) * 4;
    #pragma unroll
    for (int mt = 0; mt < 4; ++mt)
        #pragma unroll
        for (int rr = 0; rr < 4; ++rr) {
            int mrow = m0 + mt * 16 + rq + rr;
            out[(size_t)mrow * 512 + col] = acc[mt][rr] + bvv;
        }
}

// ---------------------------------------------------------------------------
// xg GEMM, H2 layers, fp32 in/out. X split hi/lo (logical K=512 over 256).
// grid = (16, CHv*4)
// ---------------------------------------------------------------------------
__global__ __launch_bounds__(256) void xg_l_kernel(
    const float* __restrict__ X, const float* __restrict__ W,
    const float* __restrict__ bias, float* __restrict__ out, int t0)
{
    __shared__ __align__(16) u16 As[64][40];
    __shared__ __align__(16) u16 Bs[64][40];
    int tid = threadIdx.x;
    int bx = blockIdx.x;          // 0..15
    int by = blockIdx.y;
    int m0 = by * 64, n0 = bx * 64;
    int r  = tid >> 2;
    int kc = (tid & 3) * 8;
    int m  = m0 + r;
    int tl = m >> 8, bb = m & 255;
    const float* arow = X + ((size_t)((t0 + tl) * 256 + bb) * 256);
    const float* brow = W + ((size_t)(n0 + r) * 256);

    f32x4 acc[4];
    #pragma unroll
    for (int i = 0; i < 4; ++i) acc[i] = (f32x4){0.f, 0.f, 0.f, 0.f};
    int lane = tid & 63, w = tid >> 6;
    int fr_ = lane & 15, kb0 = (lane >> 4) * 8;

    for (int kt = 0; kt < 16; ++kt) {
        int sc = (kt & 7) * 32 + kc;       // source col 0..255
        bool lo = kt >= 8;
        f32x4 va = *(const f32x4*)(arow + sc);
        f32x4 vb = *(const f32x4*)(arow + sc + 4);
        f32x4 wa = *(const f32x4*)(brow + sc);
        f32x4 wb = *(const f32x4*)(brow + sc + 4);
        bf16x8 hv, wv;
        #pragma unroll
        for (int i = 0; i < 8; ++i) {
            float v = (i < 4) ? va[i] : vb[i - 4];
            u16 hi = f2bf(v);
            hv[i] = (short)(lo ? f2bf(v - bf2f(hi)) : hi);
            float wf = (i < 4) ? wa[i] : wb[i - 4];
            wv[i] = (short)f2bf(wf);
        }
        *(bf16x8*)&As[r][kc] = hv;
        *(bf16x8*)&Bs[r][kc] = wv;
        __syncthreads();
        bf16x8 bfrg = *(const bf16x8*)&Bs[w * 16 + fr_][kb0];
        #pragma unroll
        for (int mt = 0; mt < 4; ++mt) {
            bf16x8 afrg = *(const bf16x8*)&As[mt * 16 + fr_][kb0];
            acc[mt] = mfma16(afrg, bfrg, acc[mt]);
        }
        __syncthreads();
    }
    int col = n0 + w * 16 + fr_;
    float bvv = bias[col];
    int rq = (lane >> 4) * 4;
    #pragma unroll
    for (int mt = 0; mt < 4; ++mt)
        #pragma unroll
        for (int rr = 0; rr < 4; ++rr) {
            int mrow = m0 + mt * 16 + rq + rr;
            out[(size_t)mrow * 1024 + col] = acc[mt][rr] + bvv;
        }
}

// ---------------------------------------------------------------------------
// layernorm over 256 channels, one wave per row. RESID adds R first. In-place.
// ---------------------------------------------------------------------------
template<int RESID>
__global__ __launch_bounds__(256) void ln_kernel(
    float* __restrict__ X, const float* __restrict__ R,
    const float* __restrict__ gw, const float* __restrict__ bw)
{
    int row  = blockIdx.x * 4 + (threadIdx.x >> 6);
    int lane = threadIdx.x & 63;
    float* xr = X + (size_t)row * 256;
    f32x4 v = *(const f32x4*)(xr + lane * 4);
    if (RESID) {
        f32x4 u = *(const f32x4*)(R + (size_t)row * 256 + lane * 4);
        v += u;
    }
    float s = v[0] + v[1] + v[2] + v[3];
    #pragma unroll
    for (int mm = 1; mm < 64; mm <<= 1) s += __shfl_xor(s, mm, 64);
    float mu = s * (1.0f / 256.0f);
    f32x4 e = v - mu;
    float q = e[0]*e[0] + e[1]*e[1] + e[2]*e[2] + e[3]*e[3];
    #pragma unroll
    for (int mm = 1; mm < 64; mm <<= 1) q += __shfl_xor(q, mm, 64);
    float rs = rsqrtf(q * (1.0f / 256.0f) + 1e-5f);
    int c0 = lane * 4;
    f32x4 o;
    #pragma unroll
    for (int i = 0; i < 4; ++i) o[i] = e[i] * rs * gw[c0 + i] + bw[c0 + i];
    *(f32x4*)(xr + lane * 4) = o;
}

// ---------------------------------------------------------------------------
// Persistent LSTM recurrence over one time chunk [s0,s1).
// MODE 0: bi H=128 layer, 256 wgs: bid<128 fwd, else rev.
//         Per dir: 32 groups x GROUP=4 wgs; MB=8 samples, JC=32 h-cols/wg.
// MODE 1: H2 layer -> xout. 16 groups x GROUP=16; MB=16, JC=16.
// MODE 2: H2 layer -> y at t==lastidx[b] (bn+relu, fp32 out).
// Whh LDS-resident. h exchange: each element is ONE 64-bit relaxed
// agent-scope atomic word [tag=t+1 | h_lo_bf16 | h_hi_bf16]. 8B single-copy
// atomicity means data+tag arrive together — no flags, no fences, no
// inter-address write-ordering assumption (r5's relaxed-flag race: vmcnt
// drain does not order h-stores vs flag-store at the IC across XCDs;
// r4's release fence: buffer_wbl2 per step thrashed L2 at 11.2 us/step).
// Back-pressure: group is all-to-all, so a wg can't overwrite slot (t&1)
// (end of its step t+1) before every wg finished reading it (their step-t
// read precedes the step-t store it needs) — distance-2 buffering is safe.
// Tags unique per step (1..256), equality-tested; 0xAA ws-poison never
// matches. c in registers, persisted in cbuf across chunk launches.
// Grid = 256 wgs <= 256 CUs -> co-resident, no deadlock.
// ---------------------------------------------------------------------------
template<int MODE>
__global__ __launch_bounds__(256) void recur_kernel(
    const float* __restrict__ xg0, const float* __restrict__ xg1,
    const float* __restrict__ whh0, const float* __restrict__ whh1,
    float* __restrict__ cb0, float* __restrict__ cb1,
    u64* hb0, u64* hb1,
    float* __restrict__ xout, float* __restrict__ yout,
    const int* __restrict__ lastidx,
    const float* __restrict__ bng, const float* __restrict__ bnb,
    int s0, int s1)
{
    constexpr int MB    = (MODE == 0) ? 8 : 16;    // samples per group
    constexpr int JC    = (MODE == 0) ? 32 : 16;   // h-cols per wg
    constexpr int GROUP = (MODE == 0) ? 4 : 16;    // wgs per group
    constexpr int K     = (MODE == 0) ? 128 : 256; // hidden size
    constexpr int NW    = 4 * JC;                  // gate rows per wg
    constexpr int M     = 2 * MB;                  // hi+lo stacked rows
    constexpr int N4    = 4 * K;                   // xg row width
    constexpr int CNT   = MB * K / 256;            // h words per thread

    __shared__ __align__(16) u16  Wl[NW][K + 8];
    __shared__ __align__(16) u16  Al[M][K + 8];
    __shared__ __align__(16) float Gl[M][NW + 4];

    int tid = threadIdx.x, lane = tid & 63, w = tid >> 6;
    int bid = blockIdx.x;

    const float* xg; const float* whh; float* cb; u64* hb;
    int coloff = 0, rev = 0, lb;
    if (MODE == 0) {
        if (bid < 128) { lb = bid;       xg = xg0; whh = whh0; cb = cb0; hb = hb0; coloff = 0;   rev = 0; }
        else           { lb = bid - 128; xg = xg1; whh = whh1; cb = cb1; hb = hb1; coloff = 128; rev = 1; }
    } else { lb = bid; xg = xg0; whh = whh0; cb = cb0; hb = hb0; }
    int group = lb / GROUP;
    int cw    = lb % GROUP;
    u64* hbg = hb + (size_t)group * (2 * MB * K);

    // stage Whh slice (fp32 -> bf16): LDS row n=g*JC+jj <- Whh[g*K + cw*JC+jj, :]
    for (int idx = tid; idx < NW * (K / 8); idx += 256) {
        int n = idx / (K / 8), kv = (idx % (K / 8)) * 8;
        int g = n / JC, jj = n % JC;
        const float* src = whh + (size_t)(g * K + cw * JC + jj) * K + kv;
        f32x4 a = *(const f32x4*)src;
        f32x4 b = *(const f32x4*)(src + 4);
        bf16x8 wv;
        #pragma unroll
        for (int i = 0; i < 8; ++i) wv[i] = (short)f2bf((i < 4) ? a[i] : b[i - 4]);
        *(bf16x8*)&Wl[n][kv] = wv;
    }

    int s   = tid / JC;            // sample-local 0..MB-1
    int jc  = tid % JC;
    int bsamp = group * MB + s;
    int col   = cw * JC + jc;
    float c = (s0 > 0) ? cb[(size_t)bsamp * K + col] : 0.f;
    int lastb = -1; float bngv = 0.f, bnbv = 0.f;
    if (MODE == 2) {
        bool is64 = (lastidx[1] | lastidx[3] | lastidx[5] | lastidx[7] |
                     lastidx[9] | lastidx[11] | lastidx[13] | lastidx[15]) == 0;
        lastb = is64 ? lastidx[2 * bsamp] : lastidx[bsamp];
        bngv = bng[col] * rsqrtf(1.0f + 1e-5f);
        bnbv = bnb[col];
    }
    int fr_ = lane & 15, kb0 = (lane >> 4) * 8, rq = (lane >> 4) * 4;
    __syncthreads();

    for (int t = s0; t < s1; ++t) {
        int xrow = rev ? (s1 - 1 - t) : (t - s0);
        const float* xp = xg + ((size_t)(xrow * 256 + bsamp)) * N4 + col;
        float xv0 = xp[0], xv1 = xp[K], xv2 = xp[2 * K], xv3 = xp[3 * K];
        float g0, g1, g2, g3;

        if (t > 0) {
            // poll the 64-bit h words until every tag == t
            u64* hsrc = hbg + (size_t)(t & 1) * (MB * K);
            u64 v[CNT];
            #pragma unroll
            for (int i = 0; i < CNT; ++i)
                v[i] = __hip_atomic_load(hsrc + tid + i * 256,
                                         __ATOMIC_RELAXED, __HIP_MEMORY_SCOPE_AGENT);
            for (;;) {
                bool ok = true;
                #pragma unroll
                for (int i = 0; i < CNT; ++i)
                    if ((unsigned int)(v[i] >> 32) != (unsigned int)t) ok = false;
                if (ok) break;
                __builtin_amdgcn_s_sleep(1);
                #pragma unroll
                for (int i = 0; i < CNT; ++i)
                    if ((unsigned int)(v[i] >> 32) != (unsigned int)t)
                        v[i] = __hip_atomic_load(hsrc + tid + i * 256,
                                                 __ATOMIC_RELAXED, __HIP_MEMORY_SCOPE_AGENT);
            }
            #pragma unroll
            for (int i = 0; i < CNT; ++i) {
                int idx = tid + i * 256;
                int sa = idx / K, k = idx % K;
                unsigned int d = (unsigned int)v[i];
                Al[sa][k]      = (u16)(d & 0xffffu);
                Al[MB + sa][k] = (u16)(d >> 16);
            }
            __syncthreads();
            f32x4 acc0 = (f32x4){0.f, 0.f, 0.f, 0.f};
            f32x4 acc1 = (f32x4){0.f, 0.f, 0.f, 0.f};
            #pragma unroll
            for (int kt = 0; kt < K / 32; ++kt) {
                int kb = kt * 32 + kb0;
                if (MODE == 0) {
                    bf16x8 a  = *(const bf16x8*)&Al[fr_][kb];
                    bf16x8 b0 = *(const bf16x8*)&Wl[(2 * w) * 16 + fr_][kb];
                    bf16x8 b1 = *(const bf16x8*)&Wl[(2 * w + 1) * 16 + fr_][kb];
                    acc0 = mfma16(a, b0, acc0);
                    acc1 = mfma16(a, b1, acc1);
                } else {
                    bf16x8 b  = *(const bf16x8*)&Wl[w * 16 + fr_][kb];
                    bf16x8 a0 = *(const bf16x8*)&Al[fr_][kb];
                    bf16x8 a1 = *(const bf16x8*)&Al[16 + fr_][kb];
                    acc0 = mfma16(a0, b, acc0);
                    acc1 = mfma16(a1, b, acc1);
                }
            }
            #pragma unroll
            for (int rr = 0; rr < 4; ++rr) {
                if (MODE == 0) {
                    Gl[rq + rr][(2 * w) * 16 + fr_]     = acc0[rr];
                    Gl[rq + rr][(2 * w + 1) * 16 + fr_] = acc1[rr];
                } else {
                    Gl[rq + rr][w * 16 + fr_]      = acc0[rr];
                    Gl[16 + rq + rr][w * 16 + fr_] = acc1[rr];
                }
            }
            __syncthreads();
            g0 = xv0 + Gl[s][0 * JC + jc] + Gl[MB + s][0 * JC + jc];
            g1 = xv1 + Gl[s][1 * JC + jc] + Gl[MB + s][1 * JC + jc];
            g2 = xv2 + Gl[s][2 * JC + jc] + Gl[MB + s][2 * JC + jc];
            g3 = xv3 + Gl[s][3 * JC + jc] + Gl[MB + s][3 * JC + jc];
        } else {
            g0 = xv0; g1 = xv1; g2 = xv2; g3 = xv3;
        }

        c = sigf(g1) * c + sigf(g0) * tanhf(g2);
        float h = sigf(g3) * tanhf(c);

        if (MODE == 0) {
            int tt = rev ? (255 - t) : t;
            xout[((size_t)tt * 256 + bsamp) * 256 + coloff + col] = h;
        } else if (MODE == 1) {
            xout[((size_t)t * 256 + bsamp) * 256 + col] = h;
        } else {
            if (t == lastb) {
                float y = h * bngv + bnbv;
                y = y > 0.f ? y : 0.f;
                yout[(size_t)bsamp * 256 + col] = y;
            }
        }

        u16 hh = f2bf(h);
        u16 hl = f2bf(h - bf2f(hh));
        u64 word = (u64)((unsigned int)hh | ((unsigned int)hl << 16))
                 | ((u64)(unsigned int)(t + 1) << 32);
        __hip_atomic_store(hbg + (size_t)((t + 1) & 1) * (MB * K) + (size_t)s * K + col,
                           word, __ATOMIC_RELAXED, __HIP_MEMORY_SCOPE_AGENT);
    }
    cb[(size_t)bsamp * K + col] = c;
}

// ---------------------------------------------------------------------------
// Launch
// ---------------------------------------------------------------------------
extern "C" void kernel_launch(void* const* d_in, const int* in_sizes, int n_in,
                              void* d_out, int out_size, void* d_ws, size_t ws_size,
                              hipStream_t stream)
{
    (void)in_sizes; (void)n_in; (void)out_size;
    const float* embed = (const float*)d_in[0];
    const int* lastidx = (const int*)d_in[1];
    const float* Wih_f = (const float*)d_in[2];
    const float* Whh_f = (const float*)d_in[3];
    const float* b_f   = (const float*)d_in[4];
    const float* Wih_r = (const float*)d_in[5];
    const float* Whh_r = (const float*)d_in[6];
    const float* b_r   = (const float*)d_in[7];
    const float* ln1g  = (const float*)d_in[8];
    const float* ln1b  = (const float*)d_in[9];
    const float* W1ih  = (const float*)d_in[10];
    const float* W1hh  = (const float*)d_in[11];
    const float* b1    = (const float*)d_in[12];
    const float* ln2g  = (const float*)d_in[13];
    const float* ln2b  = (const float*)d_in[14];
    const float* W2ih  = (const float*)d_in[15];
    const float* W2hh  = (const float*)d_in[16];
    const float* b2    = (const float*)d_in[17];
    const float* bng   = (const float*)d_in[18];
    const float* bnb   = (const float*)d_in[19];

    const size_t MiB = 1024 * 1024;
    const int  CHv = (ws_size >= 196 * MiB) ? 64 : 32;
    const int  nch = 256 / CHv;
    char* ws = (char*)d_ws;
    const size_t xgBytes = (size_t)CHv * 256 * 1024 * 4;   // 64 or 32 MiB

    float* XG  = (float*)ws;
    float* XGr = XG + (size_t)CHv * 256 * 512;             // stage-1 rev half
    float* X1  = (float*)(ws + xgBytes);                   // 64 MiB
    float* X2  = (float*)(ws + xgBytes + 64 * MiB);        // 64 MiB
    char*  p   = ws + xgBytes + 128 * MiB;
    u64* hbf = (u64*)p;                         p += 512 * 1024;   // 32g*2*1024*8
    u64* hbr = (u64*)p;                         p += 512 * 1024;
    u64* hb1 = (u64*)p;                         p += 1024 * 1024;  // 16g*2*4096*8
    u64* hb2 = (u64*)p;                         p += 1024 * 1024;
    float* cbf = (float*)p;                     p += 128 * 1024;
    float* cbr = (float*)p;                     p += 128 * 1024;
    float* cb1 = (float*)p;                     p += 256 * 1024;
    float* cb2 = (float*)p;                     // 256 KiB

    // stage 1: bidirectional H=128 LSTM -> X1 (raw concat)
    for (int i = 0; i < nch; ++i) {
        xg_fr_kernel<<<dim3(8, 2 * CHv * 4), 256, 0, stream>>>(
            embed, Wih_f, b_f, Wih_r, b_r, XG, XGr, CHv * i, 256 - CHv * (i + 1));
        recur_kernel<0><<<256, 256, 0, stream>>>(
            XG, XGr, Whh_f, Whh_r, cbf, cbr, hbf, hbr,
            X1, nullptr, nullptr, nullptr, nullptr, CHv * i, CHv * (i + 1));
    }
    ln_kernel<0><<<16384, 256, 0, stream>>>(X1, nullptr, ln1g, ln1b);

    // stage 2: H2 LSTM layer 1 -> X2 (raw)
    for (int i = 0; i < nch; ++i) {
        xg_l_kernel<<<dim3(16, CHv * 4), 256, 0, stream>>>(X1, W1ih, b1, XG, CHv * i);
        recur_kernel<1><<<256, 256, 0, stream>>>(
            XG, nullptr, W1hh, nullptr, cb1, nullptr, hb1, nullptr,
            X2, nullptr, nullptr, nullptr, nullptr, CHv * i, CHv * (i + 1));
    }
    ln_kernel<1><<<16384, 256, 0, stream>>>(X2, X1, ln2g, ln2b);

    // stage 3: H2 LSTM layer 2 -> gathered y (fp32 out)
    for (int i = 0; i < nch; ++i) {
        xg_l_kernel<<<dim3(16, CHv * 4), 256, 0, stream>>>(X2, W2ih, b2, XG, CHv * i);
        recur_kernel<2><<<256, 256, 0, stream>>>(
            XG, nullptr, W2hh, nullptr, cb2, nullptr, hb2, nullptr,
            nullptr, (float*)d_out, lastidx, bng, bnb, CHv * i, CHv * (i + 1));
    }
}

// Round 7
// 2977.994 us; speedup vs baseline: 2.7378x; 1.0303x over previous
//
#include <hip/hip_runtime.h>
#include <cstdint>
#include <cstddef>

typedef unsigned short u16;
typedef unsigned long long u64;
typedef __attribute__((ext_vector_type(8))) short bf16x8;  // 8 x bf16 (4 VGPRs)
typedef __attribute__((ext_vector_type(4))) float f32x4;

#define DEV __device__ __forceinline__

DEV float bf2f(u16 h) { union { unsigned int u; float f; } x; x.u = ((unsigned int)h) << 16; return x.f; }
DEV u16 f2bf(float f) {
    union { float f; unsigned int u; } x; x.f = f;
    unsigned int u = x.u;
    return (u16)((u + 0x7fffu + ((u >> 16) & 1u)) >> 16);   // RNE
}
DEV float sigf(float x) { return 1.0f / (1.0f + expf(-x)); }
DEV f32x4 mfma16(bf16x8 a, bf16x8 b, f32x4 c) {
    return __builtin_amdgcn_mfma_f32_16x16x32_bf16(a, b, c, 0, 0, 0);
}

// B=256, T=256, E=128, H=128 (per direction), H2=256. ALL tensors fp32.
// Time chunked (CHv = 64 or 32 chosen from ws_size) for the xg buffers.

// ---------------------------------------------------------------------------
// xg GEMM, first (bi) layer, fp32 in/out. (unchanged from r6)
// ---------------------------------------------------------------------------
__global__ __launch_bounds__(256) void xg_fr_kernel(
    const float* __restrict__ embed,
    const float* __restrict__ Wf, const float* __restrict__ bf_,
    const float* __restrict__ Wr, const float* __restrict__ br_,
    float* __restrict__ xgf, float* __restrict__ xgr, int t0f, int t0r)
{
    __shared__ __align__(16) u16 As[64][40];
    __shared__ __align__(16) u16 Bs[64][40];
    int tid = threadIdx.x;
    int bx = blockIdx.x;
    int by = blockIdx.y;
    int half = gridDim.y >> 1;
    bool isR = by >= half;
    int m0 = (by - (isR ? half : 0)) * 64;
    const float* W    = isR ? Wr  : Wf;
    const float* bias = isR ? br_ : bf_;
    float* out        = isR ? xgr : xgf;
    int tbase         = isR ? t0r : t0f;
    int n0 = bx * 64;

    int r  = tid >> 2;
    int kc = (tid & 3) * 8;
    int m  = m0 + r;
    int tl = m >> 8, bb = m & 255;
    const float* arow = embed + ((size_t)(bb * 256 + (tbase + tl)) * 128);
    const float* brow = W + ((size_t)(n0 + r) * 128);

    f32x4 acc[4];
    #pragma unroll
    for (int i = 0; i < 4; ++i) acc[i] = (f32x4){0.f, 0.f, 0.f, 0.f};
    int lane = tid & 63, w = tid >> 6;
    int fr_ = lane & 15, kb0 = (lane >> 4) * 8;

    for (int kt = 0; kt < 8; ++kt) {
        int sc = (kt & 3) * 32 + kc;
        bool lo = kt >= 4;
        f32x4 va = *(const f32x4*)(arow + sc);
        f32x4 vb = *(const f32x4*)(arow + sc + 4);
        f32x4 wa = *(const f32x4*)(brow + sc);
        f32x4 wb = *(const f32x4*)(brow + sc + 4);
        bf16x8 hv, wv;
        #pragma unroll
        for (int i = 0; i < 8; ++i) {
            float v = (i < 4) ? va[i] : vb[i - 4];
            u16 hi = f2bf(v);
            hv[i] = (short)(lo ? f2bf(v - bf2f(hi)) : hi);
            float wf = (i < 4) ? wa[i] : wb[i - 4];
            wv[i] = (short)f2bf(wf);
        }
        *(bf16x8*)&As[r][kc] = hv;
        *(bf16x8*)&Bs[r][kc] = wv;
        __syncthreads();
        bf16x8 bfrg = *(const bf16x8*)&Bs[w * 16 + fr_][kb0];
        #pragma unroll
        for (int mt = 0; mt < 4; ++mt) {
            bf16x8 afrg = *(const bf16x8*)&As[mt * 16 + fr_][kb0];
            acc[mt] = mfma16(afrg, bfrg, acc[mt]);
        }
        __syncthreads();
    }
    int col = n0 + w * 16 + fr_;
    float bvv = bias[col];
    int rq = (lane >> 4) * 4;
    #pragma unroll
    for (int mt = 0; mt < 4; ++mt)
        #pragma unroll
        for (int rr = 0; rr < 4; ++rr) {
            int mrow = m0 + mt * 16 + rq + rr;
            out[(size_t)mrow * 512 + col] = acc[mt][rr] + bvv;
        }
}

// ---------------------------------------------------------------------------
// xg GEMM, H2 layers, fp32 in/out. (unchanged from r6)
// ---------------------------------------------------------------------------
__global__ __launch_bounds__(256) void xg_l_kernel(
    const float* __restrict__ X, const float* __restrict__ W,
    const float* __restrict__ bias, float* __restrict__ out, int t0)
{
    __shared__ __align__(16) u16 As[64][40];
    __shared__ __align__(16) u16 Bs[64][40];
    int tid = threadIdx.x;
    int bx = blockIdx.x;
    int by = blockIdx.y;
    int m0 = by * 64, n0 = bx * 64;
    int r  = tid >> 2;
    int kc = (tid & 3) * 8;
    int m  = m0 + r;
    int tl = m >> 8, bb = m & 255;
    const float* arow = X + ((size_t)((t0 + tl) * 256 + bb) * 256);
    const float* brow = W + ((size_t)(n0 + r) * 256);

    f32x4 acc[4];
    #pragma unroll
    for (int i = 0; i < 4; ++i) acc[i] = (f32x4){0.f, 0.f, 0.f, 0.f};
    int lane = tid & 63, w = tid >> 6;
    int fr_ = lane & 15, kb0 = (lane >> 4) * 8;

    for (int kt = 0; kt < 16; ++kt) {
        int sc = (kt & 7) * 32 + kc;
        bool lo = kt >= 8;
        f32x4 va = *(const f32x4*)(arow + sc);
        f32x4 vb = *(const f32x4*)(arow + sc + 4);
        f32x4 wa = *(const f32x4*)(brow + sc);
        f32x4 wb = *(const f32x4*)(brow + sc + 4);
        bf16x8 hv, wv;
        #pragma unroll
        for (int i = 0; i < 8; ++i) {
            float v = (i < 4) ? va[i] : vb[i - 4];
            u16 hi = f2bf(v);
            hv[i] = (short)(lo ? f2bf(v - bf2f(hi)) : hi);
            float wf = (i < 4) ? wa[i] : wb[i - 4];
            wv[i] = (short)f2bf(wf);
        }
        *(bf16x8*)&As[r][kc] = hv;
        *(bf16x8*)&Bs[r][kc] = wv;
        __syncthreads();
        bf16x8 bfrg = *(const bf16x8*)&Bs[w * 16 + fr_][kb0];
        #pragma unroll
        for (int mt = 0; mt < 4; ++mt) {
            bf16x8 afrg = *(const bf16x8*)&As[mt * 16 + fr_][kb0];
            acc[mt] = mfma16(afrg, bfrg, acc[mt]);
        }
        __syncthreads();
    }
    int col = n0 + w * 16 + fr_;
    float bvv = bias[col];
    int rq = (lane >> 4) * 4;
    #pragma unroll
    for (int mt = 0; mt < 4; ++mt)
        #pragma unroll
        for (int rr = 0; rr < 4; ++rr) {
            int mrow = m0 + mt * 16 + rq + rr;
            out[(size_t)mrow * 1024 + col] = acc[mt][rr] + bvv;
        }
}

// ---------------------------------------------------------------------------
// layernorm over 256 channels. (unchanged from r6)
// ---------------------------------------------------------------------------
template<int RESID>
__global__ __launch_bounds__(256) void ln_kernel(
    float* __restrict__ X, const float* __restrict__ R,
    const float* __restrict__ gw, const float* __restrict__ bw)
{
    int row  = blockIdx.x * 4 + (threadIdx.x >> 6);
    int lane = threadIdx.x & 63;
    float* xr = X + (size_t)row * 256;
    f32x4 v = *(const f32x4*)(xr + lane * 4);
    if (RESID) {
        f32x4 u = *(const f32x4*)(R + (size_t)row * 256 + lane * 4);
        v += u;
    }
    float s = v[0] + v[1] + v[2] + v[3];
    #pragma unroll
    for (int mm = 1; mm < 64; mm <<= 1) s += __shfl_xor(s, mm, 64);
    float mu = s * (1.0f / 256.0f);
    f32x4 e = v - mu;
    float q = e[0]*e[0] + e[1]*e[1] + e[2]*e[2] + e[3]*e[3];
    #pragma unroll
    for (int mm = 1; mm < 64; mm <<= 1) q += __shfl_xor(q, mm, 64);
    float rs = rsqrtf(q * (1.0f / 256.0f) + 1e-5f);
    int c0 = lane * 4;
    f32x4 o;
    #pragma unroll
    for (int i = 0; i < 4; ++i) o[i] = e[i] * rs * gw[c0 + i] + bw[c0 + i];
    *(f32x4*)(xr + lane * 4) = o;
}

// ---------------------------------------------------------------------------
// Stage-1 recurrence (H=128): GROUP=1 — whole recurrence for 8 samples of one
// direction in ONE wg. Whh in VGPRs (8x4 bf16x8 frags/wave = 128 VGPRs),
// h in LDS (hi/lo rows), NO cross-wg exchange. h persisted fp32 to hp at the
// chunk boundary. Grid = 64 wgs (32/dir).
// ---------------------------------------------------------------------------
__global__ __launch_bounds__(256) void recur1_kernel(
    const float* __restrict__ xgf, const float* __restrict__ xgr,
    const float* __restrict__ whhf, const float* __restrict__ whhr,
    float* __restrict__ cbf, float* __restrict__ cbr,
    float* __restrict__ hpf, float* __restrict__ hpr,
    float* __restrict__ xout, int s0, int s1)
{
    constexpr int K = 128, MB = 8, M = 16, NW = 512, N4 = 512;
    __shared__ __align__(16) u16  Al[M][K + 8];
    __shared__ __align__(16) float Gl[M][NW + 4];

    int tid = threadIdx.x, lane = tid & 63, w = tid >> 6;
    int fr_ = lane & 15, kb0 = (lane >> 4) * 8, rq = (lane >> 4) * 4;
    int bid = blockIdx.x;
    int dir = bid >> 5, gidx = bid & 31;
    const float* xg  = dir ? xgr  : xgf;
    const float* whh = dir ? whhr : whhf;
    float* cb = dir ? cbr : cbf;
    float* hp = dir ? hpr : hpf;
    int coloff = dir ? 128 : 0;

    // Whh -> VGPR B-fragments: wave w owns gate rows [(w*8+nb)*16+fr_]
    bf16x8 bf[8][4];
    #pragma unroll
    for (int nb = 0; nb < 8; ++nb) {
        int nl = (w * 8 + nb) * 16 + fr_;          // 0..511
        int g = nl >> 7, jj = nl & 127;
        const float* src = whh + (size_t)(g * K + jj) * K;
        #pragma unroll
        for (int kt = 0; kt < 4; ++kt) {
            f32x4 a = *(const f32x4*)(src + kt * 32 + kb0);
            f32x4 b = *(const f32x4*)(src + kt * 32 + kb0 + 4);
            bf16x8 wv;
            #pragma unroll
            for (int i = 0; i < 8; ++i) wv[i] = (short)f2bf((i < 4) ? a[i] : b[i - 4]);
            bf[nb][kt] = wv;
        }
    }

    // gate threads: 4 (sample,col) pairs each
    int jc = tid & 127, sb = tid >> 7;             // sb in 0..1
    float c[4];
    int bs[4];
    #pragma unroll
    for (int p = 0; p < 4; ++p) {
        int sp = sb + 2 * p;
        bs[p] = gidx * 8 + sp;
        c[p] = (s0 > 0) ? cb[(size_t)bs[p] * K + jc] : 0.f;
    }
    if (s0 > 0) {  // preload h from persist buffer into Al (hi/lo)
        for (int idx = tid; idx < MB * K; idx += 256) {
            int sa = idx >> 7, k = idx & 127;
            float v = hp[(size_t)(gidx * 8 + sa) * K + k];
            u16 hh = f2bf(v);
            Al[sa][k] = hh;
            Al[8 + sa][k] = f2bf(v - bf2f(hh));
        }
    }
    __syncthreads();

    for (int t = s0; t < s1; ++t) {
        int xrow = dir ? (s1 - 1 - t) : (t - s0);
        float xv[4][4];
        #pragma unroll
        for (int p = 0; p < 4; ++p) {
            const float* xp = xg + ((size_t)(xrow * 256 + bs[p])) * N4 + jc;
            #pragma unroll
            for (int j = 0; j < 4; ++j) xv[p][j] = xp[j * K];
        }
        if (t > 0) {
            f32x4 acc[8];
            #pragma unroll
            for (int nb = 0; nb < 8; ++nb) acc[nb] = (f32x4){0.f, 0.f, 0.f, 0.f};
            #pragma unroll
            for (int kt = 0; kt < 4; ++kt) {
                bf16x8 a = *(const bf16x8*)&Al[fr_][kt * 32 + kb0];
                #pragma unroll
                for (int nb = 0; nb < 8; ++nb) acc[nb] = mfma16(a, bf[nb][kt], acc[nb]);
            }
            #pragma unroll
            for (int nb = 0; nb < 8; ++nb)
                #pragma unroll
                for (int rr = 0; rr < 4; ++rr)
                    Gl[rq + rr][(w * 8 + nb) * 16 + fr_] = acc[nb][rr];
            __syncthreads();
        }
        #pragma unroll
        for (int p = 0; p < 4; ++p) {
            int sp = sb + 2 * p;
            float g0 = xv[p][0], g1 = xv[p][1], g2 = xv[p][2], g3 = xv[p][3];
            if (t > 0) {
                g0 += Gl[sp][0 * K + jc] + Gl[8 + sp][0 * K + jc];
                g1 += Gl[sp][1 * K + jc] + Gl[8 + sp][1 * K + jc];
                g2 += Gl[sp][2 * K + jc] + Gl[8 + sp][2 * K + jc];
                g3 += Gl[sp][3 * K + jc] + Gl[8 + sp][3 * K + jc];
            }
            c[p] = sigf(g1) * c[p] + sigf(g0) * tanhf(g2);
            float h = sigf(g3) * tanhf(c[p]);
            int tt = dir ? (255 - t) : t;
            xout[((size_t)tt * 256 + bs[p]) * 256 + coloff + jc] = h;
            u16 hh = f2bf(h);
            Al[sp][jc] = hh;
            Al[8 + sp][jc] = f2bf(h - bf2f(hh));
            if (t == s1 - 1) hp[(size_t)bs[p] * K + jc] = h;
        }
        __syncthreads();
    }
    #pragma unroll
    for (int p = 0; p < 4; ++p) cb[(size_t)bs[p] * K + jc] = c[p];
}

// ---------------------------------------------------------------------------
// H2 recurrence (K=256): GROUP=4, JC=64, MB=8, 32 groups x 4 wgs = 128 wgs.
// Whh slice in VGPRs (4x8 frags/wave = 128 VGPRs); LDS holds only Al/Gl.
// h exchange: 64-bit relaxed agent-scope atomic words [tag | lo | hi]
// (r6-verified protocol; volume/step = 256*GROUP*K*8B, 4x less than r6).
// OUTY 0: write h to xout. OUTY 1: write y at t==lastidx[b].
// ---------------------------------------------------------------------------
template<int OUTY>
__global__ __launch_bounds__(256) void recur2_kernel(
    const float* __restrict__ xg, const float* __restrict__ whh,
    float* __restrict__ cb, u64* hb,
    float* __restrict__ xout, float* __restrict__ yout,
    const int* __restrict__ lastidx,
    const float* __restrict__ bng, const float* __restrict__ bnb,
    int s0, int s1)
{
    constexpr int K = 256, MB = 8, JC = 64, NW = 256, M = 16, N4 = 1024;
    constexpr int CNT = MB * K / 256;   // 8 poll words per thread
    __shared__ __align__(16) u16  Al[M][K + 8];
    __shared__ __align__(16) float Gl[M][NW + 4];

    int tid = threadIdx.x, lane = tid & 63, w = tid >> 6;
    int fr_ = lane & 15, kb0 = (lane >> 4) * 8, rq = (lane >> 4) * 4;
    int bid = blockIdx.x;
    int group = bid >> 2, cw = bid & 3;
    u64* hbg = hb + (size_t)group * (2 * MB * K);

    // Whh slice -> VGPR B-fragments: wave w owns rows [(w*4+nb)*16+fr_] of NW
    bf16x8 bf[4][8];
    #pragma unroll
    for (int nb = 0; nb < 4; ++nb) {
        int nl = (w * 4 + nb) * 16 + fr_;          // 0..255
        int g = nl >> 6, jj = nl & 63;
        const float* src = whh + (size_t)(g * K + cw * JC + jj) * K;
        #pragma unroll
        for (int kt = 0; kt < 8; ++kt) {
            f32x4 a = *(const f32x4*)(src + kt * 32 + kb0);
            f32x4 b = *(const f32x4*)(src + kt * 32 + kb0 + 4);
            bf16x8 wv;
            #pragma unroll
            for (int i = 0; i < 8; ++i) wv[i] = (short)f2bf((i < 4) ? a[i] : b[i - 4]);
            bf[nb][kt] = wv;
        }
    }

    // gate threads: 2 (sample,col) pairs each
    int jc = tid & 63, sb = tid >> 6;              // sb in 0..3
    int col = cw * JC + jc;
    float c[2];
    int bs[2], lastb[2] = { -1, -1 };
    float bngv = 0.f, bnbv = 0.f;
    #pragma unroll
    for (int p = 0; p < 2; ++p) {
        int sp = sb + 4 * p;
        bs[p] = group * 8 + sp;
        c[p] = (s0 > 0) ? cb[(size_t)bs[p] * K + col] : 0.f;
    }
    if (OUTY) {
        bool is64 = (lastidx[1] | lastidx[3] | lastidx[5] | lastidx[7] |
                     lastidx[9] | lastidx[11] | lastidx[13] | lastidx[15]) == 0;
        lastb[0] = is64 ? lastidx[2 * bs[0]] : lastidx[bs[0]];
        lastb[1] = is64 ? lastidx[2 * bs[1]] : lastidx[bs[1]];
        bngv = bng[col] * rsqrtf(1.0f + 1e-5f);
        bnbv = bnb[col];
    }

    for (int t = s0; t < s1; ++t) {
        int xrow = t - s0;
        float xv[2][4];
        #pragma unroll
        for (int p = 0; p < 2; ++p) {
            const float* xp = xg + ((size_t)(xrow * 256 + bs[p])) * N4 + col;
            #pragma unroll
            for (int j = 0; j < 4; ++j) xv[p][j] = xp[j * K];
        }
        if (t > 0) {
            u64* hsrc = hbg + (size_t)(t & 1) * (MB * K);
            u64 v[CNT];
            #pragma unroll
            for (int i = 0; i < CNT; ++i)
                v[i] = __hip_atomic_load(hsrc + tid + i * 256,
                                         __ATOMIC_RELAXED, __HIP_MEMORY_SCOPE_AGENT);
            for (;;) {
                bool ok = true;
                #pragma unroll
                for (int i = 0; i < CNT; ++i)
                    if ((unsigned int)(v[i] >> 32) != (unsigned int)t) ok = false;
                if (ok) break;
                __builtin_amdgcn_s_sleep(1);
                #pragma unroll
                for (int i = 0; i < CNT; ++i)
                    if ((unsigned int)(v[i] >> 32) != (unsigned int)t)
                        v[i] = __hip_atomic_load(hsrc + tid + i * 256,
                                                 __ATOMIC_RELAXED, __HIP_MEMORY_SCOPE_AGENT);
            }
            #pragma unroll
            for (int i = 0; i < CNT; ++i) {
                int idx = tid + i * 256;
                int sa = idx >> 8, k = idx & 255;
                unsigned int d = (unsigned int)v[i];
                Al[sa][k]     = (u16)(d & 0xffffu);
                Al[8 + sa][k] = (u16)(d >> 16);
            }
            __syncthreads();
            f32x4 acc[4];
            #pragma unroll
            for (int nb = 0; nb < 4; ++nb) acc[nb] = (f32x4){0.f, 0.f, 0.f, 0.f};
            #pragma unroll
            for (int kt = 0; kt < 8; ++kt) {
                bf16x8 a = *(const bf16x8*)&Al[fr_][kt * 32 + kb0];
                #pragma unroll
                for (int nb = 0; nb < 4; ++nb) acc[nb] = mfma16(a, bf[nb][kt], acc[nb]);
            }
            #pragma unroll
            for (int nb = 0; nb < 4; ++nb)
                #pragma unroll
                for (int rr = 0; rr < 4; ++rr)
                    Gl[rq + rr][(w * 4 + nb) * 16 + fr_] = acc[nb][rr];
            __syncthreads();
        }
        #pragma unroll
        for (int p = 0; p < 2; ++p) {
            int sp = sb + 4 * p;
            float g0 = xv[p][0], g1 = xv[p][1], g2 = xv[p][2], g3 = xv[p][3];
            if (t > 0) {
                g0 += Gl[sp][0 * JC + jc] + Gl[8 + sp][0 * JC + jc];
                g1 += Gl[sp][1 * JC + jc] + Gl[8 + sp][1 * JC + jc];
                g2 += Gl[sp][2 * JC + jc] + Gl[8 + sp][2 * JC + jc];
                g3 += Gl[sp][3 * JC + jc] + Gl[8 + sp][3 * JC + jc];
            }
            c[p] = sigf(g1) * c[p] + sigf(g0) * tanhf(g2);
            float h = sigf(g3) * tanhf(c[p]);
            if (OUTY == 0) {
                xout[((size_t)t * 256 + bs[p]) * 256 + col] = h;
            } else {
                if (t == lastb[p]) {
                    float y = h * bngv + bnbv;
                    y = y > 0.f ? y : 0.f;
                    yout[(size_t)bs[p] * 256 + col] = y;
                }
            }
            u16 hh = f2bf(h);
            u16 hl = f2bf(h - bf2f(hh));
            u64 word = (u64)((unsigned int)hh | ((unsigned int)hl << 16))
                     | ((u64)(unsigned int)(t + 1) << 32);
            __hip_atomic_store(hbg + (size_t)((t + 1) & 1) * (MB * K) + (size_t)sp * K + col,
                               word, __ATOMIC_RELAXED, __HIP_MEMORY_SCOPE_AGENT);
        }
    }
    #pragma unroll
    for (int p = 0; p < 2; ++p) cb[(size_t)bs[p] * K + col] = c[p];
}

// ---------------------------------------------------------------------------
// Launch
// ---------------------------------------------------------------------------
extern "C" void kernel_launch(void* const* d_in, const int* in_sizes, int n_in,
                              void* d_out, int out_size, void* d_ws, size_t ws_size,
                              hipStream_t stream)
{
    (void)in_sizes; (void)n_in; (void)out_size;
    const float* embed = (const float*)d_in[0];
    const int* lastidx = (const int*)d_in[1];
    const float* Wih_f = (const float*)d_in[2];
    const float* Whh_f = (const float*)d_in[3];
    const float* b_f   = (const float*)d_in[4];
    const float* Wih_r = (const float*)d_in[5];
    const float* Whh_r = (const float*)d_in[6];
    const float* b_r   = (const float*)d_in[7];
    const float* ln1g  = (const float*)d_in[8];
    const float* ln1b  = (const float*)d_in[9];
    const float* W1ih  = (const float*)d_in[10];
    const float* W1hh  = (const float*)d_in[11];
    const float* b1    = (const float*)d_in[12];
    const float* ln2g  = (const float*)d_in[13];
    const float* ln2b  = (const float*)d_in[14];
    const float* W2ih  = (const float*)d_in[15];
    const float* W2hh  = (const float*)d_in[16];
    const float* b2    = (const float*)d_in[17];
    const float* bng   = (const float*)d_in[18];
    const float* bnb   = (const float*)d_in[19];

    const size_t MiB = 1024 * 1024;
    const int  CHv = (ws_size >= 196 * MiB) ? 64 : 32;   // r6 confirmed >=196 MiB path
    const int  nch = 256 / CHv;
    char* ws = (char*)d_ws;
    const size_t xgBytes = (size_t)CHv * 256 * 1024 * 4;

    float* XG  = (float*)ws;
    float* XGr = XG + (size_t)CHv * 256 * 512;             // stage-1 rev half
    float* X1  = (float*)(ws + xgBytes);                   // 64 MiB
    float* X2  = (float*)(ws + xgBytes + 64 * MiB);        // 64 MiB
    char*  p   = ws + xgBytes + 128 * MiB;
    u64* hb1 = (u64*)p;                         p += 1024 * 1024;  // 32g*2*2048*8
    u64* hb2 = (u64*)p;                         p += 1024 * 1024;
    float* cbf = (float*)p;                     p += 128 * 1024;
    float* cbr = (float*)p;                     p += 128 * 1024;
    float* cb1 = (float*)p;                     p += 256 * 1024;
    float* cb2 = (float*)p;                     p += 256 * 1024;
    float* hpf = (float*)p;                     p += 128 * 1024;
    float* hpr = (float*)p;                     // 128 KiB

    // stage 1: bidirectional H=128 LSTM -> X1 (raw concat)
    for (int i = 0; i < nch; ++i) {
        xg_fr_kernel<<<dim3(8, 2 * CHv * 4), 256, 0, stream>>>(
            embed, Wih_f, b_f, Wih_r, b_r, XG, XGr, CHv * i, 256 - CHv * (i + 1));
        recur1_kernel<<<64, 256, 0, stream>>>(
            XG, XGr, Whh_f, Whh_r, cbf, cbr, hpf, hpr,
            X1, CHv * i, CHv * (i + 1));
    }
    ln_kernel<0><<<16384, 256, 0, stream>>>(X1, nullptr, ln1g, ln1b);

    // stage 2: H2 LSTM layer 1 -> X2 (raw)
    for (int i = 0; i < nch; ++i) {
        xg_l_kernel<<<dim3(16, CHv * 4), 256, 0, stream>>>(X1, W1ih, b1, XG, CHv * i);
        recur2_kernel<0><<<128, 256, 0, stream>>>(
            XG, W1hh, cb1, hb1,
            X2, nullptr, nullptr, nullptr, nullptr, CHv * i, CHv * (i + 1));
    }
    ln_kernel<1><<<16384, 256, 0, stream>>>(X2, X1, ln2g, ln2b);

    // stage 3: H2 LSTM layer 2 -> gathered y (fp32 out)
    for (int i = 0; i < nch; ++i) {
        xg_l_kernel<<<dim3(16, CHv * 4), 256, 0, stream>>>(X2, W2ih, b2, XG, CHv * i);
        recur2_kernel<1><<<128, 256, 0, stream>>>(
            XG, W2hh, cb2, hb2,
            nullptr, (float*)d_out, lastidx, bng, bnb, CHv * i, CHv * (i + 1));
    }
}

// Round 9
// 2557.220 us; speedup vs baseline: 3.1883x; 1.1645x over previous
//
#include <hip/hip_runtime.h>
#include <cstdint>
#include <cstddef>

typedef unsigned short u16;
typedef unsigned long long u64;
typedef __attribute__((ext_vector_type(8))) short bf16x8;  // 8 x bf16 (4 VGPRs)
typedef __attribute__((ext_vector_type(4))) float f32x4;

#define DEV __device__ __forceinline__

DEV float bf2f(u16 h) { union { unsigned int u; float f; } x; x.u = ((unsigned int)h) << 16; return x.f; }
DEV u16 f2bf(float f) {
    union { float f; unsigned int u; } x; x.f = f;
    unsigned int u = x.u;
    return (u16)((u + 0x7fffu + ((u >> 16) & 1u)) >> 16);   // RNE
}
// fast gate math: __expf + v_rcp_f32; rel err ~1e-6 << bf16 weight rounding
DEV float fsig(float x)  { float e = __expf(-x);      return __builtin_amdgcn_rcpf(1.0f + e); }
DEV float ftanh(float x) { float e = __expf(2.0f * x); return 1.0f - 2.0f * __builtin_amdgcn_rcpf(e + 1.0f); }
DEV f32x4 mfma16(bf16x8 a, bf16x8 b, f32x4 c) {
    return __builtin_amdgcn_mfma_f32_16x16x32_bf16(a, b, c, 0, 0, 0);
}

// B=256, T=256, E=128, H=128 (per direction), H2=256. ALL tensors fp32.
// Time chunked (CHv = 64 or 32 chosen from ws_size) for the xg buffers.

// ---------------------------------------------------------------------------
// xg GEMM, first (bi) layer, fp32 in/out. (unchanged from r7)
// ---------------------------------------------------------------------------
__global__ __launch_bounds__(256) void xg_fr_kernel(
    const float* __restrict__ embed,
    const float* __restrict__ Wf, const float* __restrict__ bf_,
    const float* __restrict__ Wr, const float* __restrict__ br_,
    float* __restrict__ xgf, float* __restrict__ xgr, int t0f, int t0r)
{
    __shared__ __align__(16) u16 As[64][40];
    __shared__ __align__(16) u16 Bs[64][40];
    int tid = threadIdx.x;
    int bx = blockIdx.x;
    int by = blockIdx.y;
    int half = gridDim.y >> 1;
    bool isR = by >= half;
    int m0 = (by - (isR ? half : 0)) * 64;
    const float* W    = isR ? Wr  : Wf;
    const float* bias = isR ? br_ : bf_;
    float* out        = isR ? xgr : xgf;
    int tbase         = isR ? t0r : t0f;
    int n0 = bx * 64;

    int r  = tid >> 2;
    int kc = (tid & 3) * 8;
    int m  = m0 + r;
    int tl = m >> 8, bb = m & 255;
    const float* arow = embed + ((size_t)(bb * 256 + (tbase + tl)) * 128);
    const float* brow = W + ((size_t)(n0 + r) * 128);

    f32x4 acc[4];
    #pragma unroll
    for (int i = 0; i < 4; ++i) acc[i] = (f32x4){0.f, 0.f, 0.f, 0.f};
    int lane = tid & 63, w = tid >> 6;
    int fr_ = lane & 15, kb0 = (lane >> 4) * 8;

    for (int kt = 0; kt < 8; ++kt) {
        int sc = (kt & 3) * 32 + kc;
        bool lo = kt >= 4;
        f32x4 va = *(const f32x4*)(arow + sc);
        f32x4 vb = *(const f32x4*)(arow + sc + 4);
        f32x4 wa = *(const f32x4*)(brow + sc);
        f32x4 wb = *(const f32x4*)(brow + sc + 4);
        bf16x8 hv, wv;
        #pragma unroll
        for (int i = 0; i < 8; ++i) {
            float v = (i < 4) ? va[i] : vb[i - 4];
            u16 hi = f2bf(v);
            hv[i] = (short)(lo ? f2bf(v - bf2f(hi)) : hi);
            float wf = (i < 4) ? wa[i] : wb[i - 4];
            wv[i] = (short)f2bf(wf);
        }
        *(bf16x8*)&As[r][kc] = hv;
        *(bf16x8*)&Bs[r][kc] = wv;
        __syncthreads();
        bf16x8 bfrg = *(const bf16x8*)&Bs[w * 16 + fr_][kb0];
        #pragma unroll
        for (int mt = 0; mt < 4; ++mt) {
            bf16x8 afrg = *(const bf16x8*)&As[mt * 16 + fr_][kb0];
            acc[mt] = mfma16(afrg, bfrg, acc[mt]);
        }
        __syncthreads();
    }
    int col = n0 + w * 16 + fr_;
    float bvv = bias[col];
    int rq = (lane >> 4) * 4;
    #pragma unroll
    for (int mt = 0; mt < 4; ++mt)
        #pragma unroll
        for (int rr = 0; rr < 4; ++rr) {
            int mrow = m0 + mt * 16 + rq + rr;
            out[(size_t)mrow * 512 + col] = acc[mt][rr] + bvv;
        }
}

// ---------------------------------------------------------------------------
// xg GEMM, H2 layers, fp32 in/out. (unchanged from r7)
// ---------------------------------------------------------------------------
__global__ __launch_bounds__(256) void xg_l_kernel(
    const float* __restrict__ X, const float* __restrict__ W,
    const float* __restrict__ bias, float* __restrict__ out, int t0)
{
    __shared__ __align__(16) u16 As[64][40];
    __shared__ __align__(16) u16 Bs[64][40];
    int tid = threadIdx.x;
    int bx = blockIdx.x;
    int by = blockIdx.y;
    int m0 = by * 64, n0 = bx * 64;
    int r  = tid >> 2;
    int kc = (tid & 3) * 8;
    int m  = m0 + r;
    int tl = m >> 8, bb = m & 255;
    const float* arow = X + ((size_t)((t0 + tl) * 256 + bb) * 256);
    const float* brow = W + ((size_t)(n0 + r) * 256);

    f32x4 acc[4];
    #pragma unroll
    for (int i = 0; i < 4; ++i) acc[i] = (f32x4){0.f, 0.f, 0.f, 0.f};
    int lane = tid & 63, w = tid >> 6;
    int fr_ = lane & 15, kb0 = (lane >> 4) * 8;

    for (int kt = 0; kt < 16; ++kt) {
        int sc = (kt & 7) * 32 + kc;
        bool lo = kt >= 8;
        f32x4 va = *(const f32x4*)(arow + sc);
        f32x4 vb = *(const f32x4*)(arow + sc + 4);
        f32x4 wa = *(const f32x4*)(brow + sc);
        f32x4 wb = *(const f32x4*)(brow + sc + 4);
        bf16x8 hv, wv;
        #pragma unroll
        for (int i = 0; i < 8; ++i) {
            float v = (i < 4) ? va[i] : vb[i - 4];
            u16 hi = f2bf(v);
            hv[i] = (short)(lo ? f2bf(v - bf2f(hi)) : hi);
            float wf = (i < 4) ? wa[i] : wb[i - 4];
            wv[i] = (short)f2bf(wf);
        }
        *(bf16x8*)&As[r][kc] = hv;
        *(bf16x8*)&Bs[r][kc] = wv;
        __syncthreads();
        bf16x8 bfrg = *(const bf16x8*)&Bs[w * 16 + fr_][kb0];
        #pragma unroll
        for (int mt = 0; mt < 4; ++mt) {
            bf16x8 afrg = *(const bf16x8*)&As[mt * 16 + fr_][kb0];
            acc[mt] = mfma16(afrg, bfrg, acc[mt]);
        }
        __syncthreads();
    }
    int col = n0 + w * 16 + fr_;
    float bvv = bias[col];
    int rq = (lane >> 4) * 4;
    #pragma unroll
    for (int mt = 0; mt < 4; ++mt)
        #pragma unroll
        for (int rr = 0; rr < 4; ++rr) {
            int mrow = m0 + mt * 16 + rq + rr;
            out[(size_t)mrow * 1024 + col] = acc[mt][rr] + bvv;
        }
}

// ---------------------------------------------------------------------------
// layernorm over 256 channels. (unchanged from r7)
// ---------------------------------------------------------------------------
template<int RESID>
__global__ __launch_bounds__(256) void ln_kernel(
    float* __restrict__ X, const float* __restrict__ R,
    const float* __restrict__ gw, const float* __restrict__ bw)
{
    int row  = blockIdx.x * 4 + (threadIdx.x >> 6);
    int lane = threadIdx.x & 63;
    float* xr = X + (size_t)row * 256;
    f32x4 v = *(const f32x4*)(xr + lane * 4);
    if (RESID) {
        f32x4 u = *(const f32x4*)(R + (size_t)row * 256 + lane * 4);
        v += u;
    }
    float s = v[0] + v[1] + v[2] + v[3];
    #pragma unroll
    for (int mm = 1; mm < 64; mm <<= 1) s += __shfl_xor(s, mm, 64);
    float mu = s * (1.0f / 256.0f);
    f32x4 e = v - mu;
    float q = e[0]*e[0] + e[1]*e[1] + e[2]*e[2] + e[3]*e[3];
    #pragma unroll
    for (int mm = 1; mm < 64; mm <<= 1) q += __shfl_xor(q, mm, 64);
    float rs = rsqrtf(q * (1.0f / 256.0f) + 1e-5f);
    int c0 = lane * 4;
    f32x4 o;
    #pragma unroll
    for (int i = 0; i < 4; ++i) o[i] = e[i] * rs * gw[c0 + i] + bw[c0 + i];
    *(f32x4*)(xr + lane * 4) = o;
}

// ---------------------------------------------------------------------------
// Stage-1 recurrence (H=128), C-domain gate fusion, ONE barrier per step.
// One wg per 8 samples per direction; Whh in VGPRs. Wave w holds accs
// acc[g][u]: gate g, cols w*32+u*16+fr_ (C-layout col=lane&15, row=quad*4+rr).
// A rows: samples 0-7 hi, 8-15 lo. hi/lo combined with UNIFORM-operand
// shfl_xor(32) over ALL (g,u,rr) — r8's divergent-index shfl fetched the
// partner's wrong u-block (the r8 bug). Divergent SELECTION (uq) afterwards
// is a v_cndmask, not a shuffle. h double-buffered in LDS Al[2].
// Grid = 64 wgs (32/dir).
// ---------------------------------------------------------------------------
__global__ __launch_bounds__(256) void recur1_kernel(
    const float* __restrict__ xgf, const float* __restrict__ xgr,
    const float* __restrict__ whhf, const float* __restrict__ whhr,
    float* __restrict__ cbf, float* __restrict__ cbr,
    float* __restrict__ hpf, float* __restrict__ hpr,
    float* __restrict__ xout, int s0, int s1)
{
    constexpr int K = 128, N4 = 512;
    __shared__ __align__(16) u16 Al[2][16][K + 8];

    int tid = threadIdx.x, lane = tid & 63, w = tid >> 6;
    int fr_ = lane & 15, quad = lane >> 4, kb0 = quad * 8;
    int bid = blockIdx.x;
    int dir = bid >> 5, gidx = bid & 31;
    const float* xg  = dir ? xgr  : xgf;
    const float* whh = dir ? whhr : whhf;
    float* cb = dir ? cbr : cbf;
    float* hp = dir ? hpr : hpf;
    int coloff = dir ? 128 : 0;

    // Whh -> VGPR B-frags: acc (g,u) covers Whh rows g*128 + w*32 + u*16 + fr_
    bf16x8 bf[4][2][4];
    #pragma unroll
    for (int g = 0; g < 4; ++g)
        #pragma unroll
        for (int u = 0; u < 2; ++u) {
            const float* src = whh + (size_t)(g * K + w * 32 + u * 16 + fr_) * K;
            #pragma unroll
            for (int kt = 0; kt < 4; ++kt) {
                f32x4 a = *(const f32x4*)(src + kt * 32 + kb0);
                f32x4 b = *(const f32x4*)(src + kt * 32 + kb0 + 4);
                bf16x8 wv;
                #pragma unroll
                for (int i = 0; i < 8; ++i) wv[i] = (short)f2bf((i < 4) ? a[i] : b[i - 4]);
                bf[g][u][kt] = wv;
            }
        }

    int uq = quad >> 1, qrow = quad & 1;
    int colw = w * 32 + uq * 16 + fr_;        // 0..127
    int b0 = gidx * 8;
    float c[4];
    #pragma unroll
    for (int rr = 0; rr < 4; ++rr)
        c[rr] = (s0 > 0) ? cb[(size_t)(b0 + qrow * 4 + rr) * K + colw] : 0.f;

    if (s0 > 0) {   // preload h (fp32) into Al[s0&1] hi/lo
        for (int idx = tid; idx < 8 * K; idx += 256) {
            int sa = idx >> 7, k = idx & 127;
            float v = hp[(size_t)(b0 + sa) * K + k];
            u16 hh = f2bf(v);
            Al[s0 & 1][sa][k] = hh;
            Al[s0 & 1][8 + sa][k] = f2bf(v - bf2f(hh));
        }
    }
    __syncthreads();

    for (int t = s0; t < s1; ++t) {
        int xrow = dir ? (s1 - 1 - t) : (t - s0);
        float xv[4][4];
        #pragma unroll
        for (int rr = 0; rr < 4; ++rr) {
            const float* xp = xg + ((size_t)(xrow * 256 + b0 + qrow * 4 + rr)) * N4 + colw;
            #pragma unroll
            for (int g = 0; g < 4; ++g) xv[rr][g] = xp[g * K];
        }
        f32x4 acc[4][2];
        if (t > 0) {
            #pragma unroll
            for (int g = 0; g < 4; ++g)
                #pragma unroll
                for (int u = 0; u < 2; ++u) acc[g][u] = (f32x4){0.f, 0.f, 0.f, 0.f};
            #pragma unroll
            for (int kt = 0; kt < 4; ++kt) {
                bf16x8 a = *(const bf16x8*)&Al[t & 1][fr_][kt * 32 + kb0];
                #pragma unroll
                for (int g = 0; g < 4; ++g)
                    #pragma unroll
                    for (int u = 0; u < 2; ++u) acc[g][u] = mfma16(a, bf[g][u][kt], acc[g][u]);
            }
            // combine hi (quads 0,1) + lo (quads 2,3): UNIFORM indices only
            #pragma unroll
            for (int g = 0; g < 4; ++g)
                #pragma unroll
                for (int u = 0; u < 2; ++u)
                    #pragma unroll
                    for (int rr = 0; rr < 4; ++rr)
                        acc[g][u][rr] += __shfl_xor(acc[g][u][rr], 32);
        }
        int tt = dir ? (255 - t) : t;
        #pragma unroll
        for (int rr = 0; rr < 4; ++rr) {
            int s = qrow * 4 + rr;
            float gg[4];
            #pragma unroll
            for (int g = 0; g < 4; ++g) {
                float pv = (t > 0) ? (uq ? acc[g][1][rr] : acc[g][0][rr]) : 0.f;
                gg[g] = xv[rr][g] + pv;
            }
            c[rr] = fsig(gg[1]) * c[rr] + fsig(gg[0]) * ftanh(gg[2]);
            float h = fsig(gg[3]) * ftanh(c[rr]);
            u16 hh = f2bf(h);
            Al[(t + 1) & 1][s][colw] = hh;
            Al[(t + 1) & 1][8 + s][colw] = f2bf(h - bf2f(hh));
            xout[((size_t)tt * 256 + b0 + s) * 256 + coloff + colw] = h;
            if (t == s1 - 1) hp[(size_t)(b0 + s) * K + colw] = h;
        }
        __syncthreads();
    }
    #pragma unroll
    for (int rr = 0; rr < 4; ++rr)
        cb[(size_t)(b0 + qrow * 4 + rr) * K + colw] = c[rr];
}

// ---------------------------------------------------------------------------
// H2 recurrence (K=256): GROUP=4, JC=64, MB=8, 32 groups x 4 wgs = 128 wgs.
// C-domain gate fusion, ONE barrier per step. Wave w holds acc[g]: gate g,
// cols cw*64 + w*16 + fr_. hi/lo combined with UNIFORM-operand shfl_xor(32)
// over all (g,rr) — r8's divergent-rr shfl fetched the partner's wrong
// sample (the r8 bug); selection by rhalf afterwards is a v_cndmask.
// h exchange: r6-verified 64-bit relaxed agent-atomic words [tag|lo|hi];
// poll doubles as the cross-step Al-reuse fence. Hot spin.
// OUTY 0: write h to xout. OUTY 1: write y at t==lastidx[b].
// ---------------------------------------------------------------------------
template<int OUTY>
__global__ __launch_bounds__(256) void recur2_kernel(
    const float* __restrict__ xg, const float* __restrict__ whh,
    float* __restrict__ cb, u64* hb,
    float* __restrict__ xout, float* __restrict__ yout,
    const int* __restrict__ lastidx,
    const float* __restrict__ bng, const float* __restrict__ bnb,
    int s0, int s1)
{
    constexpr int K = 256, MB = 8, N4 = 1024;
    constexpr int CNT = MB * K / 256;   // 8 poll words per thread
    __shared__ __align__(16) u16 Al[16][K + 8];

    int tid = threadIdx.x, lane = tid & 63, w = tid >> 6;
    int fr_ = lane & 15, quad = lane >> 4, kb0 = quad * 8;
    int bid = blockIdx.x;
    int group = bid >> 2, cw = bid & 3;
    u64* hbg = hb + (size_t)group * (2 * MB * K);
    int col = cw * 64 + w * 16 + fr_;         // 0..255

    // Whh -> VGPR B-frags: acc g covers Whh rows g*256 + col
    bf16x8 bf[4][8];
    #pragma unroll
    for (int g = 0; g < 4; ++g) {
        const float* src = whh + (size_t)(g * 256 + col) * K;
        #pragma unroll
        for (int kt = 0; kt < 8; ++kt) {
            f32x4 a = *(const f32x4*)(src + kt * 32 + kb0);
            f32x4 b = *(const f32x4*)(src + kt * 32 + kb0 + 4);
            bf16x8 wv;
            #pragma unroll
            for (int i = 0; i < 8; ++i) wv[i] = (short)f2bf((i < 4) ? a[i] : b[i - 4]);
            bf[g][kt] = wv;
        }
    }

    int qrow = quad & 1, rhalf = quad >> 1;
    int sp[2], bs[2]; float c[2];
    #pragma unroll
    for (int j = 0; j < 2; ++j) {
        sp[j] = qrow * 4 + rhalf * 2 + j;     // sample-local 0..7
        bs[j] = group * 8 + sp[j];
        c[j] = (s0 > 0) ? cb[(size_t)bs[j] * K + col] : 0.f;
    }
    int lastb[2] = { -1, -1 };
    float bngv = 0.f, bnbv = 0.f;
    if (OUTY) {
        bool is64 = (lastidx[1] | lastidx[3] | lastidx[5] | lastidx[7] |
                     lastidx[9] | lastidx[11] | lastidx[13] | lastidx[15]) == 0;
        lastb[0] = is64 ? lastidx[2 * bs[0]] : lastidx[bs[0]];
        lastb[1] = is64 ? lastidx[2 * bs[1]] : lastidx[bs[1]];
        bngv = bng[col] * rsqrtf(1.0f + 1e-5f);
        bnbv = bnb[col];
    }

    for (int t = s0; t < s1; ++t) {
        int xrow = t - s0;
        float xv[2][4];
        #pragma unroll
        for (int j = 0; j < 2; ++j) {
            const float* xp = xg + ((size_t)(xrow * 256 + bs[j])) * N4 + col;
            #pragma unroll
            for (int g = 0; g < 4; ++g) xv[j][g] = xp[g * 256];
        }
        f32x4 acc[4];
        if (t > 0) {
            u64* hsrc = hbg + (size_t)(t & 1) * (MB * K);
            u64 v[CNT];
            #pragma unroll
            for (int i = 0; i < CNT; ++i)
                v[i] = __hip_atomic_load(hsrc + tid + i * 256,
                                         __ATOMIC_RELAXED, __HIP_MEMORY_SCOPE_AGENT);
            for (;;) {
                bool ok = true;
                #pragma unroll
                for (int i = 0; i < CNT; ++i)
                    if ((unsigned int)(v[i] >> 32) != (unsigned int)t) ok = false;
                if (ok) break;
                #pragma unroll
                for (int i = 0; i < CNT; ++i)
                    if ((unsigned int)(v[i] >> 32) != (unsigned int)t)
                        v[i] = __hip_atomic_load(hsrc + tid + i * 256,
                                                 __ATOMIC_RELAXED, __HIP_MEMORY_SCOPE_AGENT);
            }
            // stage: word idx = tid + i*256 -> sample i, col tid
            #pragma unroll
            for (int i = 0; i < CNT; ++i) {
                unsigned int d = (unsigned int)v[i];
                Al[i][tid]     = (u16)(d & 0xffffu);
                Al[8 + i][tid] = (u16)(d >> 16);
            }
            __syncthreads();
            #pragma unroll
            for (int g = 0; g < 4; ++g) acc[g] = (f32x4){0.f, 0.f, 0.f, 0.f};
            #pragma unroll
            for (int kt = 0; kt < 8; ++kt) {
                bf16x8 a = *(const bf16x8*)&Al[fr_][kt * 32 + kb0];
                #pragma unroll
                for (int g = 0; g < 4; ++g) acc[g] = mfma16(a, bf[g][kt], acc[g]);
            }
            // combine hi (quads 0,1) + lo (quads 2,3): UNIFORM indices only
            #pragma unroll
            for (int g = 0; g < 4; ++g)
                #pragma unroll
                for (int rr = 0; rr < 4; ++rr)
                    acc[g][rr] += __shfl_xor(acc[g][rr], 32);
        }
        #pragma unroll
        for (int j = 0; j < 2; ++j) {
            float gg[4];
            #pragma unroll
            for (int g = 0; g < 4; ++g) {
                float pv = (t > 0) ? (rhalf ? acc[g][2 + j] : acc[g][j]) : 0.f;
                gg[g] = xv[j][g] + pv;
            }
            c[j] = fsig(gg[1]) * c[j] + fsig(gg[0]) * ftanh(gg[2]);
            float h = fsig(gg[3]) * ftanh(c[j]);
            u16 hh = f2bf(h);
            u16 hl = f2bf(h - bf2f(hh));
            u64 word = (u64)((unsigned int)hh | ((unsigned int)hl << 16))
                     | ((u64)(unsigned int)(t + 1) << 32);
            __hip_atomic_store(hbg + (size_t)((t + 1) & 1) * (MB * K) + (size_t)sp[j] * K + col,
                               word, __ATOMIC_RELAXED, __HIP_MEMORY_SCOPE_AGENT);
            if (OUTY == 0) {
                xout[((size_t)t * 256 + bs[j]) * 256 + col] = h;
            } else if (t == lastb[j]) {
                float y = h * bngv + bnbv;
                y = y > 0.f ? y : 0.f;
                yout[(size_t)bs[j] * 256 + col] = y;
            }
        }
    }
    #pragma unroll
    for (int j = 0; j < 2; ++j) cb[(size_t)bs[j] * K + col] = c[j];
}

// ---------------------------------------------------------------------------
// Launch
// ---------------------------------------------------------------------------
extern "C" void kernel_launch(void* const* d_in, const int* in_sizes, int n_in,
                              void* d_out, int out_size, void* d_ws, size_t ws_size,
                              hipStream_t stream)
{
    (void)in_sizes; (void)n_in; (void)out_size;
    const float* embed = (const float*)d_in[0];
    const int* lastidx = (const int*)d_in[1];
    const float* Wih_f = (const float*)d_in[2];
    const float* Whh_f = (const float*)d_in[3];
    const float* b_f   = (const float*)d_in[4];
    const float* Wih_r = (const float*)d_in[5];
    const float* Whh_r = (const float*)d_in[6];
    const float* b_r   = (const float*)d_in[7];
    const float* ln1g  = (const float*)d_in[8];
    const float* ln1b  = (const float*)d_in[9];
    const float* W1ih  = (const float*)d_in[10];
    const float* W1hh  = (const float*)d_in[11];
    const float* b1    = (const float*)d_in[12];
    const float* ln2g  = (const float*)d_in[13];
    const float* ln2b  = (const float*)d_in[14];
    const float* W2ih  = (const float*)d_in[15];
    const float* W2hh  = (const float*)d_in[16];
    const float* b2    = (const float*)d_in[17];
    const float* bng   = (const float*)d_in[18];
    const float* bnb   = (const float*)d_in[19];

    const size_t MiB = 1024 * 1024;
    const int  CHv = (ws_size >= 196 * MiB) ? 64 : 32;
    const int  nch = 256 / CHv;
    char* ws = (char*)d_ws;
    const size_t xgBytes = (size_t)CHv * 256 * 1024 * 4;

    float* XG  = (float*)ws;
    float* XGr = XG + (size_t)CHv * 256 * 512;             // stage-1 rev half
    float* X1  = (float*)(ws + xgBytes);                   // 64 MiB
    float* X2  = (float*)(ws + xgBytes + 64 * MiB);        // 64 MiB
    char*  p   = ws + xgBytes + 128 * MiB;
    u64* hb1 = (u64*)p;                         p += 1024 * 1024;
    u64* hb2 = (u64*)p;                         p += 1024 * 1024;
    float* cbf = (float*)p;                     p += 128 * 1024;
    float* cbr = (float*)p;                     p += 128 * 1024;
    float* cb1 = (float*)p;                     p += 256 * 1024;
    float* cb2 = (float*)p;                     p += 256 * 1024;
    float* hpf = (float*)p;                     p += 128 * 1024;
    float* hpr = (float*)p;                     // 128 KiB

    // stage 1: bidirectional H=128 LSTM -> X1 (raw concat)
    for (int i = 0; i < nch; ++i) {
        xg_fr_kernel<<<dim3(8, 2 * CHv * 4), 256, 0, stream>>>(
            embed, Wih_f, b_f, Wih_r, b_r, XG, XGr, CHv * i, 256 - CHv * (i + 1));
        recur1_kernel<<<64, 256, 0, stream>>>(
            XG, XGr, Whh_f, Whh_r, cbf, cbr, hpf, hpr,
            X1, CHv * i, CHv * (i + 1));
    }
    ln_kernel<0><<<16384, 256, 0, stream>>>(X1, nullptr, ln1g, ln1b);

    // stage 2: H2 LSTM layer 1 -> X2 (raw)
    for (int i = 0; i < nch; ++i) {
        xg_l_kernel<<<dim3(16, CHv * 4), 256, 0, stream>>>(X1, W1ih, b1, XG, CHv * i);
        recur2_kernel<0><<<128, 256, 0, stream>>>(
            XG, W1hh, cb1, hb1,
            X2, nullptr, nullptr, nullptr, nullptr, CHv * i, CHv * (i + 1));
    }
    ln_kernel<1><<<16384, 256, 0, stream>>>(X2, X1, ln2g, ln2b);

    // stage 3: H2 LSTM layer 2 -> gathered y (fp32 out)
    for (int i = 0; i < nch; ++i) {
        xg_l_kernel<<<dim3(16, CHv * 4), 256, 0, stream>>>(X2, W2ih, b2, XG, CHv * i);
        recur2_kernel<1><<<128, 256, 0, stream>>>(
            XG, W2hh, cb2, hb2,
            nullptr, (float*)d_out, lastidx, bng, bnb, CHv * i, CHv * (i + 1));
    }
}